// Round 4
// baseline (493.217 us; speedup 1.0000x reference)
//
#include <hip/hip_runtime.h>
#include <cstdint>
#include <cstddef>

typedef _Float16 f16;
typedef _Float16 f16x8 __attribute__((ext_vector_type(8)));
typedef _Float16 f16x4 __attribute__((ext_vector_type(4)));
typedef float f32x16 __attribute__((ext_vector_type(16)));
typedef float f32x4 __attribute__((ext_vector_type(4)));

static constexpr int NPTS = 262144;

// Repacked weight offsets (in halfs). Each "tile" is 512 halfs = 64 lanes x 8.
// Fragment layout per tile (kt, ct): value = W[k][ch], k = kt*16 + (l>>5)*8 + j,
// ch = ct*32 + (l&31). Tiles ordered [segment][kt][ct], contiguous.
static constexpr int OFF_W0    = 0;        // 4 kt x 8 ct
static constexpr int OFF_W1    = 16384;    // 16 x 8
static constexpr int OFF_W2    = 81920;
static constexpr int OFF_W3    = 147456;
static constexpr int OFF_W4    = 212992;
static constexpr int OFF_W5    = 278528;   // w5b (16x8) then w5a (4x8), contiguous = 20 slices
static constexpr int OFF_W6    = 360448;
static constexpr int OFF_W7    = 425984;
static constexpr int OFF_FEAT  = 491520;
static constexpr int OFF_VIEWS = 557056;   // viewsA (16x4) then viewsB (2x4) = 18 slices of 2048
static constexpr int OFF_RGB   = 593920;   // 8 x 1

struct Seg { const float* src; int k0, rv, fo, ct, t0; };
struct RepParams { Seg seg[13]; f16* rep; };

__global__ void repack_kernel(RepParams P) {
  int tile = blockIdx.x;
  int s = 0;
  #pragma unroll
  for (int i = 1; i < 13; ++i)
    if (tile >= P.seg[i].t0) s = i;
  const Seg sg = P.seg[s];
  int local = tile - sg.t0;
  int kt = local / sg.ct;
  int ct = local - kt * sg.ct;
  int l = threadIdx.x;
  int ch = ct * 32 + (l & 31);
  int kbase = kt * 16 + ((l >> 5) << 3);
  f16x8 v;
  #pragma unroll
  for (int j = 0; j < 8; ++j) {
    int k = kbase + j;
    float val = 0.f;
    if (k < sg.rv && ch < sg.fo) val = sg.src[(size_t)(sg.k0 + k) * sg.fo + ch];
    v[j] = (f16)val;
  }
  *(f16x8*)(P.rep + (size_t)tile * 512 + (size_t)l * 8) = v;
}

struct MainParams {
  const float* x;
  const float* b[8];
  const float* feat_b;
  const float* alpha_w;
  const float* alpha_b;
  const float* views_b;
  const float* rgb_b;
  const f16* rep;
  float* out;
};

// Activation LDS addressing: [pt<128][256ch] f16, 512 B rows, XOR swizzle to
// avoid 32-way bank conflicts on the stride-512 ds_read_b128 B-fragment reads.
__device__ __forceinline__ int act_off(int pt, int kbyte) {
  return pt * 512 + (kbyte ^ ((pt & 15) << 4));
}

// Standard 256-out layer; block = 4 waves x 128 pts. Wave w computes
// ch [64w, 64w+64) x all 128 pts: acc[c][p], c<2 (ct = 2w+c), p<4 (pt tile).
// A-frags straight from global (L1/L2-resident repack) into registers, full
// 16-kt unroll for deep load pipelining. Skip-connection input (KTX kt-tiles
// of pos, 63 ch) gathered from x per-kt to cap register pressure.
template<int KTA, int KTX, bool RELU>
__device__ __forceinline__ void layer_std128(
    const f16* repL, const float* bias,
    f16* act, const float* xrow0, int lane, int w)
{
  const int l31 = lane & 31;
  const int ln5 = lane >> 5;
  const int chb = w * 64;

  f32x16 acc[2][4];
  #pragma unroll
  for (int c = 0; c < 2; ++c) {
    #pragma unroll
    for (int g = 0; g < 4; ++g) {
      f32x4 bv = *(const f32x4*)(bias + chb + c * 32 + g * 8 + (ln5 << 2));
      #pragma unroll
      for (int p = 0; p < 4; ++p) {
        #pragma unroll
        for (int q = 0; q < 4; ++q) acc[c][p][g * 4 + q] = bv[q];
      }
    }
  }

  // Skip-connection part first (pos frags live only one j-step).
  #pragma unroll
  for (int j = 0; j < KTX; ++j) {
    f16x8 pf[4];
    #pragma unroll
    for (int p = 0; p < 4; ++p) {
      const float* row = xrow0 + (size_t)(p * 32 + l31) * 90;
      #pragma unroll
      for (int jj = 0; jj < 8; ++jj) {
        int c = j * 16 + ln5 * 8 + jj;
        pf[p][jj] = (f16)((c < 63) ? row[c] : 0.f);
      }
    }
    f16x8 a[2];
    #pragma unroll
    for (int c = 0; c < 2; ++c)
      a[c] = *(const f16x8*)(repL + (size_t)((KTA + j) * 8 + 2 * w + c) * 512 + (size_t)lane * 8);
    #pragma unroll
    for (int c = 0; c < 2; ++c)
      #pragma unroll
      for (int p = 0; p < 4; ++p)
        acc[c][p] = __builtin_amdgcn_mfma_f32_32x32x16_f16(a[c], pf[p], acc[c][p], 0, 0, 0);
  }

  __syncthreads();  // prev epilogue writes -> visible to our B reads

  #pragma unroll
  for (int kt = 0; kt < KTA; ++kt) {
    f16x8 a[2], bfr[4];
    #pragma unroll
    for (int c = 0; c < 2; ++c)
      a[c] = *(const f16x8*)(repL + (size_t)(kt * 8 + 2 * w + c) * 512 + (size_t)lane * 8);
    #pragma unroll
    for (int p = 0; p < 4; ++p)
      bfr[p] = *(const f16x8*)((const char*)act + act_off(p * 32 + l31, (kt * 16 + ln5 * 8) * 2));
    #pragma unroll
    for (int c = 0; c < 2; ++c)
      #pragma unroll
      for (int p = 0; p < 4; ++p)
        acc[c][p] = __builtin_amdgcn_mfma_f32_32x32x16_f16(a[c], bfr[p], acc[c][p], 0, 0, 0);
  }

  __syncthreads();  // all B reads done -> safe to overwrite act in place

  // Epilogue: C row = (r&3) + 8*(r>>2) + 4*(l>>5), col = l&31 (pt).
  #pragma unroll
  for (int c = 0; c < 2; ++c) {
    #pragma unroll
    for (int p = 0; p < 4; ++p) {
      int pt = p * 32 + l31;
      #pragma unroll
      for (int g = 0; g < 4; ++g) {
        f16x4 h;
        #pragma unroll
        for (int q = 0; q < 4; ++q) {
          float v = acc[c][p][g * 4 + q];
          if (RELU) v = fmaxf(v, 0.f);
          h[q] = (f16)v;
        }
        int ch = chb + c * 32 + g * 8 + (ln5 << 2);
        *(f16x4*)((char*)act + act_off(pt, ch * 2)) = h;
      }
    }
  }
}

// Views layer: in = feature(256 from act) + views(27 gathered), out = 128 ch.
// Wave w -> ch [32w, 32w+32) x 128 pts.
__device__ __forceinline__ void layer_views128(
    const f16* repL, const float* bias, f16* act,
    const float* xrow0, int lane, int w)
{
  const int l31 = lane & 31;
  const int ln5 = lane >> 5;
  const int chb = w * 32;

  f32x16 acc[4];
  #pragma unroll
  for (int g = 0; g < 4; ++g) {
    f32x4 bv = *(const f32x4*)(bias + chb + g * 8 + (ln5 << 2));
    #pragma unroll
    for (int p = 0; p < 4; ++p)
      #pragma unroll
      for (int q = 0; q < 4; ++q) acc[p][g * 4 + q] = bv[q];
  }

  // Views part first.
  #pragma unroll
  for (int j = 0; j < 2; ++j) {
    f16x8 vf[4];
    #pragma unroll
    for (int p = 0; p < 4; ++p) {
      const float* row = xrow0 + (size_t)(p * 32 + l31) * 90;
      #pragma unroll
      for (int jj = 0; jj < 8; ++jj) {
        int c = j * 16 + ln5 * 8 + jj;
        vf[p][jj] = (f16)((c < 27) ? row[63 + c] : 0.f);
      }
    }
    f16x8 a = *(const f16x8*)(repL + (size_t)((16 + j) * 4 + w) * 512 + (size_t)lane * 8);
    #pragma unroll
    for (int p = 0; p < 4; ++p)
      acc[p] = __builtin_amdgcn_mfma_f32_32x32x16_f16(a, vf[p], acc[p], 0, 0, 0);
  }

  __syncthreads();

  #pragma unroll
  for (int kt = 0; kt < 16; ++kt) {
    f16x8 a = *(const f16x8*)(repL + (size_t)(kt * 4 + w) * 512 + (size_t)lane * 8);
    f16x8 bfr[4];
    #pragma unroll
    for (int p = 0; p < 4; ++p)
      bfr[p] = *(const f16x8*)((const char*)act + act_off(p * 32 + l31, (kt * 16 + ln5 * 8) * 2));
    #pragma unroll
    for (int p = 0; p < 4; ++p)
      acc[p] = __builtin_amdgcn_mfma_f32_32x32x16_f16(a, bfr[p], acc[p], 0, 0, 0);
  }

  __syncthreads();

  #pragma unroll
  for (int p = 0; p < 4; ++p) {
    int pt = p * 32 + l31;
    #pragma unroll
    for (int g = 0; g < 4; ++g) {
      f16x4 h;
      #pragma unroll
      for (int q = 0; q < 4; ++q) {
        float v = fmaxf(acc[p][g * 4 + q], 0.f);
        h[q] = (f16)v;
      }
      int ch = chb + g * 8 + (ln5 << 2);
      *(f16x4*)((char*)act + act_off(pt, ch * 2)) = h;
    }
  }
}

// alpha = y . alpha_w + alpha_b. 2 threads per point (128 pts, 256 threads).
__device__ __forceinline__ void alpha_pass(const f16* act, const float* aw,
                                           const float* ab, float* alds, int tid)
{
  __syncthreads();
  int pt = tid >> 1;
  int h = tid & 1;
  float s = 0.f;
  #pragma unroll
  for (int i = 0; i < 16; ++i) {
    int k0 = h * 128 + i * 8;
    f16x8 v = *(const f16x8*)((const char*)act + act_off(pt, k0 * 2));
    f32x4 wa = *(const f32x4*)(aw + k0);
    f32x4 wb = *(const f32x4*)(aw + k0 + 4);
    #pragma unroll
    for (int q = 0; q < 4; ++q) {
      s += (float)v[q] * wa[q];
      s += (float)v[q + 4] * wb[q];
    }
  }
  s += __shfl_xor(s, 1);
  if (h == 0) alds[pt] = s + ab[0];
}

// rgb (128 -> 3 via one padded 32-ch MFMA tile per wave) + packed store.
__device__ __forceinline__ void layer_rgb_store(
    const f16* repL, f16* act, const float* alds,
    const float* rgb_b, float* out, int pt0, int lane, int w)
{
  __syncthreads();
  f32x16 acc = {};
  #pragma unroll
  for (int kt = 0; kt < 8; ++kt) {
    f16x8 a = *(const f16x8*)(repL + (size_t)kt * 512 + (size_t)lane * 8);
    f16x8 b = *(const f16x8*)((const char*)act + act_off(w * 32 + (lane & 31), (kt * 16 + (lane >> 5) * 8) * 2));
    acc = __builtin_amdgcn_mfma_f32_32x32x16_f16(a, b, acc, 0, 0, 0);
  }
  if (lane < 32) {
    int pt = w * 32 + lane;
    float4 o;
    o.x = acc[0] + rgb_b[0];
    o.y = acc[1] + rgb_b[1];
    o.z = acc[2] + rgb_b[2];
    o.w = alds[pt];
    *(float4*)(out + (size_t)(pt0 + pt) * 4) = o;
  }
}

__global__ __launch_bounds__(256, 2) void nerf_main(MainParams P) {
  __shared__ __align__(16) f16 act[65536];   // 64 KB: [128 pt][256 k], swizzled
  __shared__ float alds[128];

  const int tid = threadIdx.x;
  const int lane = tid & 63;
  const int w = tid >> 6;
  const int pt0 = blockIdx.x * 128;
  const float* xrow0 = P.x + (size_t)pt0 * 90;

  layer_std128<0, 4, true>(P.rep + OFF_W0, P.b[0], act, xrow0, lane, w);
  layer_std128<16, 0, true>(P.rep + OFF_W1, P.b[1], act, nullptr, lane, w);
  layer_std128<16, 0, true>(P.rep + OFF_W2, P.b[2], act, nullptr, lane, w);
  layer_std128<16, 0, true>(P.rep + OFF_W3, P.b[3], act, nullptr, lane, w);
  layer_std128<16, 0, true>(P.rep + OFF_W4, P.b[4], act, nullptr, lane, w);
  layer_std128<16, 4, true>(P.rep + OFF_W5, P.b[5], act, xrow0, lane, w);
  layer_std128<16, 0, true>(P.rep + OFF_W6, P.b[6], act, nullptr, lane, w);
  layer_std128<16, 0, true>(P.rep + OFF_W7, P.b[7], act, nullptr, lane, w);

  alpha_pass(act, P.alpha_w, P.alpha_b, alds, tid);

  layer_std128<16, 0, false>(P.rep + OFF_FEAT, P.feat_b, act, nullptr, lane, w);

  layer_views128(P.rep + OFF_VIEWS, P.views_b, act, xrow0, lane, w);

  layer_rgb_store(P.rep + OFF_RGB, act, alds, P.rgb_b, P.out, pt0, lane, w);

  // Second tuple output: zeros (N, 3) -> 384 floats per 128-pt block
  float* out2 = P.out + (size_t)NPTS * 4;
  if (tid < 192) {
    *(float2*)(out2 + (size_t)blockIdx.x * 384 + (size_t)tid * 2) = make_float2(0.f, 0.f);
  }
}

extern "C" void kernel_launch(void* const* d_in, const int* in_sizes, int n_in,
                              void* d_out, int out_size, void* d_ws, size_t ws_size,
                              hipStream_t stream) {
  (void)in_sizes; (void)n_in; (void)out_size; (void)ws_size;

  RepParams rp;
  rp.seg[0]  = { (const float*)d_in[1],    0,  63, 256, 8,    0 }; // w0 (pad K 63->64)
  rp.seg[1]  = { (const float*)d_in[3],    0, 256, 256, 8,   32 }; // w1
  rp.seg[2]  = { (const float*)d_in[5],    0, 256, 256, 8,  160 }; // w2
  rp.seg[3]  = { (const float*)d_in[7],    0, 256, 256, 8,  288 }; // w3
  rp.seg[4]  = { (const float*)d_in[9],    0, 256, 256, 8,  416 }; // w4
  rp.seg[5]  = { (const float*)d_in[11],  63, 256, 256, 8,  544 }; // w5 y-part (rows 63..318)
  rp.seg[6]  = { (const float*)d_in[11],   0,  63, 256, 8,  672 }; // w5 pos-part (rows 0..62)
  rp.seg[7]  = { (const float*)d_in[13],   0, 256, 256, 8,  704 }; // w6
  rp.seg[8]  = { (const float*)d_in[15],   0, 256, 256, 8,  832 }; // w7
  rp.seg[9]  = { (const float*)d_in[17],   0, 256, 256, 8,  960 }; // feat_w
  rp.seg[10] = { (const float*)d_in[21],   0, 256, 128, 4, 1088 }; // views_w feature-part
  rp.seg[11] = { (const float*)d_in[21], 256,  27, 128, 4, 1152 }; // views_w views-part
  rp.seg[12] = { (const float*)d_in[23],   0, 128,   3, 1, 1160 }; // rgb_w (pad 3->32 ch)
  rp.rep = (f16*)d_ws;
  repack_kernel<<<1168, 64, 0, stream>>>(rp);

  MainParams mp;
  mp.x = (const float*)d_in[0];
  for (int i = 0; i < 8; ++i) mp.b[i] = (const float*)d_in[2 + 2 * i];
  mp.feat_b  = (const float*)d_in[18];
  mp.alpha_w = (const float*)d_in[19];
  mp.alpha_b = (const float*)d_in[20];
  mp.views_b = (const float*)d_in[22];
  mp.rgb_b   = (const float*)d_in[24];
  mp.rep = (const f16*)d_ws;
  mp.out = (float*)d_out;
  nerf_main<<<2048, 256, 0, stream>>>(mp);
}

// Round 5
// 490.416 us; speedup vs baseline: 1.0057x; 1.0057x over previous
//
#include <hip/hip_runtime.h>
#include <cstdint>
#include <cstddef>

typedef _Float16 f16;
typedef _Float16 f16x8 __attribute__((ext_vector_type(8)));
typedef _Float16 f16x4 __attribute__((ext_vector_type(4)));
typedef float f32x16 __attribute__((ext_vector_type(16)));
typedef float f32x4 __attribute__((ext_vector_type(4)));

static constexpr int NPTS = 262144;

// Repacked weight offsets (in halfs). Each "tile" is 512 halfs = 64 lanes x 8.
// Fragment layout per tile (kt, ct): value = W[k][ch], k = kt*16 + (l>>5)*8 + j,
// ch = ct*32 + (l&31). Tiles ordered [segment][kt][ct], contiguous.
static constexpr int OFF_W0    = 0;        // 4 kt x 8 ct
static constexpr int OFF_W1    = 16384;    // 16 x 8
static constexpr int OFF_W2    = 81920;
static constexpr int OFF_W3    = 147456;
static constexpr int OFF_W4    = 212992;
static constexpr int OFF_W5    = 278528;   // w5b (16x8) then w5a (4x8), contiguous = 20 slices
static constexpr int OFF_W6    = 360448;
static constexpr int OFF_W7    = 425984;
static constexpr int OFF_FEAT  = 491520;
static constexpr int OFF_VIEWS = 557056;   // viewsA (16x4) then viewsB (2x4) = 18 slices of 2048
static constexpr int OFF_RGB   = 593920;   // 8 x 1

struct Seg { const float* src; int k0, rv, fo, ct, t0; };
struct RepParams { Seg seg[13]; f16* rep; };

__global__ void repack_kernel(RepParams P) {
  int tile = blockIdx.x;
  int s = 0;
  #pragma unroll
  for (int i = 1; i < 13; ++i)
    if (tile >= P.seg[i].t0) s = i;
  const Seg sg = P.seg[s];
  int local = tile - sg.t0;
  int kt = local / sg.ct;
  int ct = local - kt * sg.ct;
  int l = threadIdx.x;
  int ch = ct * 32 + (l & 31);
  int kbase = kt * 16 + ((l >> 5) << 3);
  f16x8 v;
  #pragma unroll
  for (int j = 0; j < 8; ++j) {
    int k = kbase + j;
    float val = 0.f;
    if (k < sg.rv && ch < sg.fo) val = sg.src[(size_t)(sg.k0 + k) * sg.fo + ch];
    v[j] = (f16)val;
  }
  *(f16x8*)(P.rep + (size_t)tile * 512 + (size_t)l * 8) = v;
}

struct MainParams {
  const float* x;
  const float* b[8];
  const float* feat_b;
  const float* alpha_w;
  const float* alpha_b;
  const float* views_b;
  const float* rgb_b;
  const f16* rep;
  float* out;
};

// Activation LDS addressing: [pt<256][256ch] f16, 512 B rows, XOR swizzle.
// B-frag ds_read_b128 verified conflict-free: bank-quad = (pt&7) spread.
__device__ __forceinline__ int act_off(int pt, int kbyte) {
  return pt * 512 + (kbyte ^ ((pt & 15) << 4));
}

// Standard 256-out layer; block = 4 waves (2ch x 2pt), wave tile 128ch x 128pt.
// acc[c][p] (c<4: ct = ci*4+c, p<4: pt-tile) = 256 f32 -> AGPRs (1 wave/SIMD,
// unified 512-reg file). A-frags from global (L2-resident repack), B from LDS.
template<int KTA, int KTX, bool RELU>
__device__ __forceinline__ void layer128(
    const f16* repL, const float* bias,
    f16* act, const float* xrow0, int lane, int ci, int pi)
{
  const int l31 = lane & 31;
  const int ln5 = lane >> 5;
  const int chb = ci * 128;
  const int ptb = pi * 128;

  f32x16 acc[4][4];
  #pragma unroll
  for (int c = 0; c < 4; ++c) {
    #pragma unroll
    for (int g = 0; g < 4; ++g) {
      f32x4 bv = *(const f32x4*)(bias + chb + c * 32 + g * 8 + (ln5 << 2));
      #pragma unroll
      for (int p = 0; p < 4; ++p) {
        #pragma unroll
        for (int q = 0; q < 4; ++q) acc[c][p][g * 4 + q] = bv[q];
      }
    }
  }

  // Skip-connection part first (pos frags live only one j-step).
  #pragma unroll
  for (int j = 0; j < KTX; ++j) {
    f16x8 pf[4];
    #pragma unroll
    for (int p = 0; p < 4; ++p) {
      const float* row = xrow0 + (size_t)(ptb + p * 32 + l31) * 90;
      #pragma unroll
      for (int jj = 0; jj < 8; ++jj) {
        int c = j * 16 + ln5 * 8 + jj;
        pf[p][jj] = (f16)((c < 63) ? row[c] : 0.f);
      }
    }
    #pragma unroll
    for (int c = 0; c < 4; ++c) {
      f16x8 a = *(const f16x8*)(repL + (size_t)((KTA + j) * 8 + ci * 4 + c) * 512 + (size_t)lane * 8);
      #pragma unroll
      for (int p = 0; p < 4; ++p)
        acc[c][p] = __builtin_amdgcn_mfma_f32_32x32x16_f16(a, pf[p], acc[c][p], 0, 0, 0);
    }
  }

  __syncthreads();  // prev epilogue writes -> visible to our B reads

  #pragma unroll
  for (int kt = 0; kt < KTA; ++kt) {
    f16x8 a[4], bfr[4];
    #pragma unroll
    for (int c = 0; c < 4; ++c)
      a[c] = *(const f16x8*)(repL + (size_t)(kt * 8 + ci * 4 + c) * 512 + (size_t)lane * 8);
    #pragma unroll
    for (int p = 0; p < 4; ++p)
      bfr[p] = *(const f16x8*)((const char*)act + act_off(ptb + p * 32 + l31, (kt * 16 + ln5 * 8) * 2));
    #pragma unroll
    for (int c = 0; c < 4; ++c)
      #pragma unroll
      for (int p = 0; p < 4; ++p)
        acc[c][p] = __builtin_amdgcn_mfma_f32_32x32x16_f16(a[c], bfr[p], acc[c][p], 0, 0, 0);
  }

  __syncthreads();  // all B reads done -> safe to overwrite act in place

  // Epilogue: C row = (r&3) + 8*(r>>2) + 4*(l>>5), col = l&31 (pt).
  #pragma unroll
  for (int c = 0; c < 4; ++c) {
    #pragma unroll
    for (int p = 0; p < 4; ++p) {
      int pt = ptb + p * 32 + l31;
      #pragma unroll
      for (int g = 0; g < 4; ++g) {
        f16x4 h;
        #pragma unroll
        for (int q = 0; q < 4; ++q) {
          float v = acc[c][p][g * 4 + q];
          if (RELU) v = fmaxf(v, 0.f);
          h[q] = (f16)v;
        }
        int ch = chb + c * 32 + g * 8 + (ln5 << 2);
        *(f16x4*)((char*)act + act_off(pt, ch * 2)) = h;
      }
    }
  }
}

// Views layer: in = feature(256 from act) + views(27 gathered), out = 128 ch.
// Wave w -> ct = w (ch 32w..32w+32), ALL 256 pts (8 pt-tiles). acc = 128 f32.
__device__ __forceinline__ void layer_views256(
    const f16* repL, const float* bias, f16* act,
    const float* xrow0, int lane, int w)
{
  const int l31 = lane & 31;
  const int ln5 = lane >> 5;
  const int chb = w * 32;

  f32x16 acc[8];
  #pragma unroll
  for (int g = 0; g < 4; ++g) {
    f32x4 bv = *(const f32x4*)(bias + chb + g * 8 + (ln5 << 2));
    #pragma unroll
    for (int p = 0; p < 8; ++p)
      #pragma unroll
      for (int q = 0; q < 4; ++q) acc[p][g * 4 + q] = bv[q];
  }

  // Views part first.
  #pragma unroll
  for (int j = 0; j < 2; ++j) {
    f16x8 a = *(const f16x8*)(repL + (size_t)((16 + j) * 4 + w) * 512 + (size_t)lane * 8);
    #pragma unroll
    for (int p = 0; p < 8; ++p) {
      f16x8 vf;
      const float* row = xrow0 + (size_t)(p * 32 + l31) * 90;
      #pragma unroll
      for (int jj = 0; jj < 8; ++jj) {
        int c = j * 16 + ln5 * 8 + jj;
        vf[jj] = (f16)((c < 27) ? row[63 + c] : 0.f);
      }
      acc[p] = __builtin_amdgcn_mfma_f32_32x32x16_f16(a, vf, acc[p], 0, 0, 0);
    }
  }

  __syncthreads();

  #pragma unroll
  for (int kt = 0; kt < 16; ++kt) {
    f16x8 a = *(const f16x8*)(repL + (size_t)(kt * 4 + w) * 512 + (size_t)lane * 8);
    #pragma unroll
    for (int p = 0; p < 8; ++p) {
      f16x8 bfr = *(const f16x8*)((const char*)act + act_off(p * 32 + l31, (kt * 16 + ln5 * 8) * 2));
      acc[p] = __builtin_amdgcn_mfma_f32_32x32x16_f16(a, bfr, acc[p], 0, 0, 0);
    }
  }

  __syncthreads();

  #pragma unroll
  for (int p = 0; p < 8; ++p) {
    int pt = p * 32 + l31;
    #pragma unroll
    for (int g = 0; g < 4; ++g) {
      f16x4 h;
      #pragma unroll
      for (int q = 0; q < 4; ++q) {
        float v = fmaxf(acc[p][g * 4 + q], 0.f);
        h[q] = (f16)v;
      }
      int ch = chb + g * 8 + (ln5 << 2);
      *(f16x4*)((char*)act + act_off(pt, ch * 2)) = h;
    }
  }
}

// alpha = y . alpha_w + alpha_b. 1 thread per point (256 pts, 256 threads).
__device__ __forceinline__ void alpha_pass(const f16* act, const float* aw,
                                           const float* ab, float* alds, int tid)
{
  __syncthreads();
  float s = 0.f;
  #pragma unroll
  for (int i = 0; i < 32; ++i) {
    int k0 = i * 8;
    f16x8 v = *(const f16x8*)((const char*)act + act_off(tid, k0 * 2));
    f32x4 wa = *(const f32x4*)(aw + k0);
    f32x4 wb = *(const f32x4*)(aw + k0 + 4);
    #pragma unroll
    for (int q = 0; q < 4; ++q) {
      s += (float)v[q] * wa[q];
      s += (float)v[q + 4] * wb[q];
    }
  }
  alds[tid] = s + ab[0];
}

// rgb (128 -> 3 via padded 32-ch MFMA): wave w handles pts [64w, 64w+64).
__device__ __forceinline__ void layer_rgb_store(
    const f16* repL, f16* act, const float* alds,
    const float* rgb_b, float* out, int pt0, int lane, int w)
{
  __syncthreads();
  f32x16 acc[2] = {};
  #pragma unroll
  for (int kt = 0; kt < 8; ++kt) {
    f16x8 a = *(const f16x8*)(repL + (size_t)kt * 512 + (size_t)lane * 8);
    #pragma unroll
    for (int p = 0; p < 2; ++p) {
      f16x8 b = *(const f16x8*)((const char*)act + act_off(w * 64 + p * 32 + (lane & 31), (kt * 16 + (lane >> 5) * 8) * 2));
      acc[p] = __builtin_amdgcn_mfma_f32_32x32x16_f16(a, b, acc[p], 0, 0, 0);
    }
  }
  if (lane < 32) {
    #pragma unroll
    for (int p = 0; p < 2; ++p) {
      int pt = w * 64 + p * 32 + lane;
      float4 o;
      o.x = acc[p][0] + rgb_b[0];
      o.y = acc[p][1] + rgb_b[1];
      o.z = acc[p][2] + rgb_b[2];
      o.w = alds[pt];
      *(float4*)(out + (size_t)(pt0 + pt) * 4) = o;
    }
  }
}

__global__ __launch_bounds__(256, 1) void nerf_main(MainParams P) {
  __shared__ __align__(16) f16 act[131072 / 2];  // 128 KB: [256 pt][256 k], swizzled
  __shared__ float alds[256];

  const int tid = threadIdx.x;
  const int lane = tid & 63;
  const int w = tid >> 6;
  const int ci = w >> 1;                 // ch-half
  const int pi = w & 1;                  // pt-half
  const int pt0 = blockIdx.x * 256;
  const float* xrow0 = P.x + (size_t)pt0 * 90;

  layer128<0, 4, true>(P.rep + OFF_W0, P.b[0], act, xrow0, lane, ci, pi);
  layer128<16, 0, true>(P.rep + OFF_W1, P.b[1], act, nullptr, lane, ci, pi);
  layer128<16, 0, true>(P.rep + OFF_W2, P.b[2], act, nullptr, lane, ci, pi);
  layer128<16, 0, true>(P.rep + OFF_W3, P.b[3], act, nullptr, lane, ci, pi);
  layer128<16, 0, true>(P.rep + OFF_W4, P.b[4], act, nullptr, lane, ci, pi);
  layer128<16, 4, true>(P.rep + OFF_W5, P.b[5], act, xrow0, lane, ci, pi);
  layer128<16, 0, true>(P.rep + OFF_W6, P.b[6], act, nullptr, lane, ci, pi);
  layer128<16, 0, true>(P.rep + OFF_W7, P.b[7], act, nullptr, lane, ci, pi);

  alpha_pass(act, P.alpha_w, P.alpha_b, alds, tid);

  layer128<16, 0, false>(P.rep + OFF_FEAT, P.feat_b, act, nullptr, lane, ci, pi);

  layer_views256(P.rep + OFF_VIEWS, P.views_b, act, xrow0, lane, w);

  layer_rgb_store(P.rep + OFF_RGB, act, alds, P.rgb_b, P.out, pt0, lane, w);

  // Second tuple output: zeros (N, 3) -> 768 floats per 256-pt block
  float* out2 = P.out + (size_t)NPTS * 4;
  if (tid < 192) {
    *(float4*)(out2 + (size_t)blockIdx.x * 768 + (size_t)tid * 4) =
        make_float4(0.f, 0.f, 0.f, 0.f);
  }
}

extern "C" void kernel_launch(void* const* d_in, const int* in_sizes, int n_in,
                              void* d_out, int out_size, void* d_ws, size_t ws_size,
                              hipStream_t stream) {
  (void)in_sizes; (void)n_in; (void)out_size; (void)ws_size;

  RepParams rp;
  rp.seg[0]  = { (const float*)d_in[1],    0,  63, 256, 8,    0 }; // w0 (pad K 63->64)
  rp.seg[1]  = { (const float*)d_in[3],    0, 256, 256, 8,   32 }; // w1
  rp.seg[2]  = { (const float*)d_in[5],    0, 256, 256, 8,  160 }; // w2
  rp.seg[3]  = { (const float*)d_in[7],    0, 256, 256, 8,  288 }; // w3
  rp.seg[4]  = { (const float*)d_in[9],    0, 256, 256, 8,  416 }; // w4
  rp.seg[5]  = { (const float*)d_in[11],  63, 256, 256, 8,  544 }; // w5 y-part (rows 63..318)
  rp.seg[6]  = { (const float*)d_in[11],   0,  63, 256, 8,  672 }; // w5 pos-part (rows 0..62)
  rp.seg[7]  = { (const float*)d_in[13],   0, 256, 256, 8,  704 }; // w6
  rp.seg[8]  = { (const float*)d_in[15],   0, 256, 256, 8,  832 }; // w7
  rp.seg[9]  = { (const float*)d_in[17],   0, 256, 256, 8,  960 }; // feat_w
  rp.seg[10] = { (const float*)d_in[21],   0, 256, 128, 4, 1088 }; // views_w feature-part
  rp.seg[11] = { (const float*)d_in[21], 256,  27, 128, 4, 1152 }; // views_w views-part
  rp.seg[12] = { (const float*)d_in[23],   0, 128,   3, 1, 1160 }; // rgb_w (pad 3->32 ch)
  rp.rep = (f16*)d_ws;
  repack_kernel<<<1168, 64, 0, stream>>>(rp);

  MainParams mp;
  mp.x = (const float*)d_in[0];
  for (int i = 0; i < 8; ++i) mp.b[i] = (const float*)d_in[2 + 2 * i];
  mp.feat_b  = (const float*)d_in[18];
  mp.alpha_w = (const float*)d_in[19];
  mp.alpha_b = (const float*)d_in[20];
  mp.views_b = (const float*)d_in[22];
  mp.rgb_b   = (const float*)d_in[24];
  mp.rep = (const f16*)d_ws;
  mp.out = (float*)d_out;
  nerf_main<<<1024, 256, 0, stream>>>(mp);
}

// Round 6
// 484.396 us; speedup vs baseline: 1.0182x; 1.0124x over previous
//
#include <hip/hip_runtime.h>
#include <cstdint>
#include <cstddef>

typedef _Float16 f16;
typedef _Float16 f16x8 __attribute__((ext_vector_type(8)));
typedef _Float16 f16x4 __attribute__((ext_vector_type(4)));
typedef float f32x16 __attribute__((ext_vector_type(16)));
typedef float f32x4 __attribute__((ext_vector_type(4)));

static constexpr int NPTS = 262144;

// Repacked weight offsets (in halfs). Each "tile" is 512 halfs = 64 lanes x 8.
// Fragment layout per tile (kt, ct): value = W[k][ch], k = kt*16 + (l>>5)*8 + j,
// ch = ct*32 + (l&31). Tiles ordered [segment][kt][ct], contiguous.
static constexpr int OFF_W0    = 0;        // 4 kt x 8 ct
static constexpr int OFF_W1    = 16384;    // 16 x 8
static constexpr int OFF_W2    = 81920;
static constexpr int OFF_W3    = 147456;
static constexpr int OFF_W4    = 212992;
static constexpr int OFF_W5    = 278528;   // w5b (16x8) then w5a (4x8), contiguous = 20 slices
static constexpr int OFF_W6    = 360448;
static constexpr int OFF_W7    = 425984;
static constexpr int OFF_FEAT  = 491520;
static constexpr int OFF_VIEWS = 557056;   // viewsA (16x4) then viewsB (2x4) = 18 slices of 2048
static constexpr int OFF_RGB   = 593920;   // 8 x 1

struct Seg { const float* src; int k0, rv, fo, ct, t0; };
struct RepParams { Seg seg[13]; f16* rep; };

__global__ void repack_kernel(RepParams P) {
  int tile = blockIdx.x;
  int s = 0;
  #pragma unroll
  for (int i = 1; i < 13; ++i)
    if (tile >= P.seg[i].t0) s = i;
  const Seg sg = P.seg[s];
  int local = tile - sg.t0;
  int kt = local / sg.ct;
  int ct = local - kt * sg.ct;
  int l = threadIdx.x;
  int ch = ct * 32 + (l & 31);
  int kbase = kt * 16 + ((l >> 5) << 3);
  f16x8 v;
  #pragma unroll
  for (int j = 0; j < 8; ++j) {
    int k = kbase + j;
    float val = 0.f;
    if (k < sg.rv && ch < sg.fo) val = sg.src[(size_t)(sg.k0 + k) * sg.fo + ch];
    v[j] = (f16)val;
  }
  *(f16x8*)(P.rep + (size_t)tile * 512 + (size_t)l * 8) = v;
}

struct MainParams {
  const float* x;
  const float* b[8];
  const float* feat_b;
  const float* alpha_w;
  const float* alpha_b;
  const float* views_b;
  const float* rgb_b;
  const f16* rep;
  float* out;
};

// Activation LDS addressing: [pt<256][256ch] f16, 512 B rows, XOR swizzle.
__device__ __forceinline__ int act_off(int pt, int kbyte) {
  return pt * 512 + (kbyte ^ ((pt & 15) << 4));
}

// Counted vmcnt wait (compile-time constant after unroll).
__device__ __forceinline__ void waitv(int n) {
  if (n == 4)      asm volatile("s_waitcnt vmcnt(4)" ::: "memory");
  else if (n == 2) asm volatile("s_waitcnt vmcnt(2)" ::: "memory");
  else if (n == 1) asm volatile("s_waitcnt vmcnt(1)" ::: "memory");
  else             asm volatile("s_waitcnt vmcnt(0)" ::: "memory");
}

#define GLOBAL_AS __attribute__((address_space(1)))
#define LDS_AS __attribute__((address_space(3)))

__device__ __forceinline__ void gload_lds16(const void* g, void* l) {
  __builtin_amdgcn_global_load_lds((const GLOBAL_AS void*)g, (LDS_AS void*)l, 16, 0, 0);
}

// Stage one 8KB weight slice (8 ct tiles) into ring slot (slice&3).
// Each wave stages its own 2KB quarter (2 x global_load_lds width-16).
__device__ __forceinline__ void stage8k(const f16* repL, f16* ring, int slice,
                                        int w, int lane) {
  int slot = slice & 3;
  const f16* g0 = repL + (size_t)slice * 4096 + w * 1024 + (size_t)lane * 8;
  f16* l0 = ring + slot * 4096 + w * 1024;
  gload_lds16(g0, l0);
  gload_lds16(g0 + 512, l0 + 512);
}

// Stage one 4KB views slice (4 ct tiles): each wave stages its own 1KB tile
// (which is exactly the tile it reads: tile index == wave index).
__device__ __forceinline__ void stage4k(const f16* repL, f16* ring, int slice,
                                        int w, int lane) {
  int slot = slice & 3;
  const f16* g0 = repL + (size_t)slice * 2048 + w * 512 + (size_t)lane * 8;
  f16* l0 = ring + slot * 4096 + w * 512;
  gload_lds16(g0, l0);
}

// 256-out layer; block = 4 waves (2ci x 2pi), wave tile 128ch x 128pt,
// acc = 256 f32 in AGPRs. A-frags from the LDS ring (staged via
// global_load_lds, counted-vmcnt pipeline, raw s_barrier per kt); B from act.
template<int KTA, int KTX, bool RELU>
__device__ __forceinline__ void layer128s(
    const f16* repL, const float* bias,
    f16* act, f16* ring, const float* xrow0,
    int lane, int w, int ci, int pi)
{
  const int l31 = lane & 31;
  const int ln5 = lane >> 5;
  const int chb = ci * 128;
  const int ptb = pi * 128;

  f32x16 acc[4][4];
  #pragma unroll
  for (int c = 0; c < 4; ++c) {
    #pragma unroll
    for (int g = 0; g < 4; ++g) {
      f32x4 bv = *(const f32x4*)(bias + chb + c * 32 + g * 8 + (ln5 << 2));
      #pragma unroll
      for (int p = 0; p < 4; ++p) {
        #pragma unroll
        for (int q = 0; q < 4; ++q) acc[c][p][g * 4 + q] = bv[q];
      }
    }
  }

  // Skip-connection part (A from global, x gathered per-kt; only L0/L5).
  #pragma unroll
  for (int j = 0; j < KTX; ++j) {
    f16x8 pf[4];
    #pragma unroll
    for (int p = 0; p < 4; ++p) {
      const float* row = xrow0 + (size_t)(ptb + p * 32 + l31) * 90;
      #pragma unroll
      for (int jj = 0; jj < 8; ++jj) {
        int c = j * 16 + ln5 * 8 + jj;
        pf[p][jj] = (f16)((c < 63) ? row[c] : 0.f);
      }
    }
    #pragma unroll
    for (int c = 0; c < 4; ++c) {
      f16x8 a = *(const f16x8*)(repL + (size_t)((KTA + j) * 8 + ci * 4 + c) * 512 + (size_t)lane * 8);
      #pragma unroll
      for (int p = 0; p < 4; ++p)
        acc[c][p] = __builtin_amdgcn_mfma_f32_32x32x16_f16(a, pf[p], acc[c][p], 0, 0, 0);
    }
  }

  if constexpr (KTA > 0) {
    stage8k(repL, ring, 0, w, lane);
    stage8k(repL, ring, 1, w, lane);
  }
  __syncthreads();  // prev epilogue visible; prologue stages drained

  if constexpr (KTA > 0) {
    #pragma unroll
    for (int kt = 0; kt < KTA; ++kt) {
      if (kt + 2 < KTA) stage8k(repL, ring, kt + 2, w, lane);
      // own-portion completion for slice kt, counted (never drains pipeline)
      waitv(kt + 2 < KTA ? 4 : (kt + 1 < KTA ? 2 : 0));
      __builtin_amdgcn_sched_barrier(0);
      __builtin_amdgcn_s_barrier();       // raw barrier: no vmcnt(0) drain
      __builtin_amdgcn_sched_barrier(0);
      const f16* ws = ring + (kt & 3) * 4096;
      f16x8 a[4], bfr[4];
      #pragma unroll
      for (int c = 0; c < 4; ++c)
        a[c] = *(const f16x8*)(ws + (ci * 4 + c) * 512 + (size_t)lane * 8);
      #pragma unroll
      for (int p = 0; p < 4; ++p)
        bfr[p] = *(const f16x8*)((const char*)act + act_off(ptb + p * 32 + l31, (kt * 16 + ln5 * 8) * 2));
      #pragma unroll
      for (int c = 0; c < 4; ++c)
        #pragma unroll
        for (int p = 0; p < 4; ++p)
          acc[c][p] = __builtin_amdgcn_mfma_f32_32x32x16_f16(a[c], bfr[p], acc[c][p], 0, 0, 0);
    }
    __syncthreads();  // all B reads done -> safe to overwrite act
  }

  // Epilogue: C row = (r&3) + 8*(r>>2) + 4*(l>>5), col = l&31 (pt).
  #pragma unroll
  for (int c = 0; c < 4; ++c) {
    #pragma unroll
    for (int p = 0; p < 4; ++p) {
      int pt = ptb + p * 32 + l31;
      #pragma unroll
      for (int g = 0; g < 4; ++g) {
        f16x4 h;
        #pragma unroll
        for (int q = 0; q < 4; ++q) {
          float v = acc[c][p][g * 4 + q];
          if (RELU) v = fmaxf(v, 0.f);
          h[q] = (f16)v;
        }
        int ch = chb + c * 32 + g * 8 + (ln5 << 2);
        *(f16x4*)((char*)act + act_off(pt, ch * 2)) = h;
      }
    }
  }
}

// Views layer: in = feature(256 from act) + views(27 gathered), out = 128 ch.
// Wave w -> ct = w, all 256 pts. Same counted-vmcnt staged pipeline (4KB slices).
__device__ __forceinline__ void layer_views256s(
    const f16* repL, const float* bias, f16* act, f16* ring,
    const float* xrow0, int lane, int w)
{
  const int l31 = lane & 31;
  const int ln5 = lane >> 5;
  const int chb = w * 32;

  f32x16 acc[8];
  #pragma unroll
  for (int g = 0; g < 4; ++g) {
    f32x4 bv = *(const f32x4*)(bias + chb + g * 8 + (ln5 << 2));
    #pragma unroll
    for (int p = 0; p < 8; ++p)
      #pragma unroll
      for (int q = 0; q < 4; ++q) acc[p][g * 4 + q] = bv[q];
  }

  // Views part first (A from global; slices 16,17 of the views segment).
  #pragma unroll
  for (int j = 0; j < 2; ++j) {
    f16x8 a = *(const f16x8*)(repL + (size_t)((16 + j) * 4 + w) * 512 + (size_t)lane * 8);
    #pragma unroll
    for (int p = 0; p < 8; ++p) {
      f16x8 vf;
      const float* row = xrow0 + (size_t)(p * 32 + l31) * 90;
      #pragma unroll
      for (int jj = 0; jj < 8; ++jj) {
        int c = j * 16 + ln5 * 8 + jj;
        vf[jj] = (f16)((c < 27) ? row[63 + c] : 0.f);
      }
      acc[p] = __builtin_amdgcn_mfma_f32_32x32x16_f16(a, vf, acc[p], 0, 0, 0);
    }
  }

  stage4k(repL, ring, 0, w, lane);
  stage4k(repL, ring, 1, w, lane);
  __syncthreads();

  #pragma unroll
  for (int kt = 0; kt < 16; ++kt) {
    if (kt + 2 < 16) stage4k(repL, ring, kt + 2, w, lane);
    waitv(kt + 2 < 16 ? 2 : (kt + 1 < 16 ? 1 : 0));
    __builtin_amdgcn_sched_barrier(0);
    __builtin_amdgcn_s_barrier();
    __builtin_amdgcn_sched_barrier(0);
    const f16* ws = ring + (kt & 3) * 4096;
    f16x8 a = *(const f16x8*)(ws + w * 512 + (size_t)lane * 8);
    #pragma unroll
    for (int p = 0; p < 8; ++p) {
      f16x8 bfr = *(const f16x8*)((const char*)act + act_off(p * 32 + l31, (kt * 16 + ln5 * 8) * 2));
      acc[p] = __builtin_amdgcn_mfma_f32_32x32x16_f16(a, bfr, acc[p], 0, 0, 0);
    }
  }
  __syncthreads();

  #pragma unroll
  for (int p = 0; p < 8; ++p) {
    int pt = p * 32 + l31;
    #pragma unroll
    for (int g = 0; g < 4; ++g) {
      f16x4 h;
      #pragma unroll
      for (int q = 0; q < 4; ++q) {
        float v = fmaxf(acc[p][g * 4 + q], 0.f);
        h[q] = (f16)v;
      }
      int ch = chb + g * 8 + (ln5 << 2);
      *(f16x4*)((char*)act + act_off(pt, ch * 2)) = h;
    }
  }
}

// alpha = y . alpha_w + alpha_b, kept in a register (thread tid <-> pt tid).
__device__ __forceinline__ float alpha_pass(const f16* act, const float* aw,
                                            const float* ab, int tid)
{
  __syncthreads();
  float s = 0.f;
  #pragma unroll
  for (int i = 0; i < 32; ++i) {
    int k0 = i * 8;
    f16x8 v = *(const f16x8*)((const char*)act + act_off(tid, k0 * 2));
    f32x4 wa = *(const f32x4*)(aw + k0);
    f32x4 wb = *(const f32x4*)(aw + k0 + 4);
    #pragma unroll
    for (int q = 0; q < 4; ++q) {
      s += (float)v[q] * wa[q];
      s += (float)v[q + 4] * wb[q];
    }
  }
  return s + ab[0];
}

// rgb (128 -> 3 via padded 32-ch MFMA): wave w handles pts [64w, 64w+64).
// alpha comes from registers via intra-wave shuffles (lane L holds pt w*64+L).
__device__ __forceinline__ void layer_rgb_store(
    const f16* repL, f16* act, float alpha_val,
    const float* rgb_b, float* out, int pt0, int lane, int w)
{
  __syncthreads();
  f32x16 acc[2] = {};
  #pragma unroll
  for (int kt = 0; kt < 8; ++kt) {
    f16x8 a = *(const f16x8*)(repL + (size_t)kt * 512 + (size_t)lane * 8);
    #pragma unroll
    for (int p = 0; p < 2; ++p) {
      f16x8 b = *(const f16x8*)((const char*)act + act_off(w * 64 + p * 32 + (lane & 31), (kt * 16 + (lane >> 5) * 8) * 2));
      acc[p] = __builtin_amdgcn_mfma_f32_32x32x16_f16(a, b, acc[p], 0, 0, 0);
    }
  }
  float aw0 = __shfl(alpha_val, lane & 31);
  float aw1 = __shfl(alpha_val, 32 + (lane & 31));
  if (lane < 32) {
    #pragma unroll
    for (int p = 0; p < 2; ++p) {
      int pt = w * 64 + p * 32 + lane;
      float4 o;
      o.x = acc[p][0] + rgb_b[0];
      o.y = acc[p][1] + rgb_b[1];
      o.z = acc[p][2] + rgb_b[2];
      o.w = (p == 0) ? aw0 : aw1;
      *(float4*)(out + (size_t)(pt0 + pt) * 4) = o;
    }
  }
}

__global__ __launch_bounds__(256, 1) void nerf_main(MainParams P) {
  // 160 KB exactly: act 128 KB ([256 pt][256 k], swizzled) + 32 KB weight ring
  __shared__ __align__(16) f16 lds[81920];
  f16* act = lds;
  f16* ring = lds + 65536;

  const int tid = threadIdx.x;
  const int lane = tid & 63;
  const int w = tid >> 6;
  const int ci = w >> 1;                 // ch-half
  const int pi = w & 1;                  // pt-half
  const int pt0 = blockIdx.x * 256;
  const float* xrow0 = P.x + (size_t)pt0 * 90;

  layer128s<0, 4, true>(P.rep + OFF_W0, P.b[0], act, ring, xrow0, lane, w, ci, pi);
  layer128s<16, 0, true>(P.rep + OFF_W1, P.b[1], act, ring, nullptr, lane, w, ci, pi);
  layer128s<16, 0, true>(P.rep + OFF_W2, P.b[2], act, ring, nullptr, lane, w, ci, pi);
  layer128s<16, 0, true>(P.rep + OFF_W3, P.b[3], act, ring, nullptr, lane, w, ci, pi);
  layer128s<16, 0, true>(P.rep + OFF_W4, P.b[4], act, ring, nullptr, lane, w, ci, pi);
  layer128s<16, 4, true>(P.rep + OFF_W5, P.b[5], act, ring, xrow0, lane, w, ci, pi);
  layer128s<16, 0, true>(P.rep + OFF_W6, P.b[6], act, ring, nullptr, lane, w, ci, pi);
  layer128s<16, 0, true>(P.rep + OFF_W7, P.b[7], act, ring, nullptr, lane, w, ci, pi);

  float alpha_val = alpha_pass(act, P.alpha_w, P.alpha_b, tid);

  layer128s<16, 0, false>(P.rep + OFF_FEAT, P.feat_b, act, ring, nullptr, lane, w, ci, pi);

  layer_views256s(P.rep + OFF_VIEWS, P.views_b, act, ring, xrow0, lane, w);

  layer_rgb_store(P.rep + OFF_RGB, act, alpha_val, P.rgb_b, P.out, pt0, lane, w);

  // Second tuple output: zeros (N, 3) -> 768 floats per 256-pt block
  float* out2 = P.out + (size_t)NPTS * 4;
  if (tid < 192) {
    *(float4*)(out2 + (size_t)blockIdx.x * 768 + (size_t)tid * 4) =
        make_float4(0.f, 0.f, 0.f, 0.f);
  }
}

extern "C" void kernel_launch(void* const* d_in, const int* in_sizes, int n_in,
                              void* d_out, int out_size, void* d_ws, size_t ws_size,
                              hipStream_t stream) {
  (void)in_sizes; (void)n_in; (void)out_size; (void)ws_size;

  RepParams rp;
  rp.seg[0]  = { (const float*)d_in[1],    0,  63, 256, 8,    0 }; // w0 (pad K 63->64)
  rp.seg[1]  = { (const float*)d_in[3],    0, 256, 256, 8,   32 }; // w1
  rp.seg[2]  = { (const float*)d_in[5],    0, 256, 256, 8,  160 }; // w2
  rp.seg[3]  = { (const float*)d_in[7],    0, 256, 256, 8,  288 }; // w3
  rp.seg[4]  = { (const float*)d_in[9],    0, 256, 256, 8,  416 }; // w4
  rp.seg[5]  = { (const float*)d_in[11],  63, 256, 256, 8,  544 }; // w5 y-part (rows 63..318)
  rp.seg[6]  = { (const float*)d_in[11],   0,  63, 256, 8,  672 }; // w5 pos-part (rows 0..62)
  rp.seg[7]  = { (const float*)d_in[13],   0, 256, 256, 8,  704 }; // w6
  rp.seg[8]  = { (const float*)d_in[15],   0, 256, 256, 8,  832 }; // w7
  rp.seg[9]  = { (const float*)d_in[17],   0, 256, 256, 8,  960 }; // feat_w
  rp.seg[10] = { (const float*)d_in[21],   0, 256, 128, 4, 1088 }; // views_w feature-part
  rp.seg[11] = { (const float*)d_in[21], 256,  27, 128, 4, 1152 }; // views_w views-part
  rp.seg[12] = { (const float*)d_in[23],   0, 128,   3, 1, 1160 }; // rgb_w (pad 3->32 ch)
  rp.rep = (f16*)d_ws;
  repack_kernel<<<1168, 64, 0, stream>>>(rp);

  MainParams mp;
  mp.x = (const float*)d_in[0];
  for (int i = 0; i < 8; ++i) mp.b[i] = (const float*)d_in[2 + 2 * i];
  mp.feat_b  = (const float*)d_in[18];
  mp.alpha_w = (const float*)d_in[19];
  mp.alpha_b = (const float*)d_in[20];
  mp.views_b = (const float*)d_in[22];
  mp.rgb_b   = (const float*)d_in[24];
  mp.rep = (const f16*)d_ws;
  mp.out = (float*)d_out;
  nerf_main<<<1024, 256, 0, stream>>>(mp);
}

// Round 7
// 449.308 us; speedup vs baseline: 1.0977x; 1.0781x over previous
//
#include <hip/hip_runtime.h>
#include <cstdint>
#include <cstddef>

typedef _Float16 f16;
typedef _Float16 f16x8 __attribute__((ext_vector_type(8)));
typedef _Float16 f16x4 __attribute__((ext_vector_type(4)));
typedef float f32x16 __attribute__((ext_vector_type(16)));
typedef float f32x4 __attribute__((ext_vector_type(4)));

static constexpr int NPTS = 262144;

// Repacked weight offsets (in halfs). Each "tile" is 512 halfs = 64 lanes x 8.
// Fragment layout per tile (kt, ct): value = W[k][ch], k = kt*16 + (l>>5)*8 + j,
// ch = ct*32 + (l&31). Tiles ordered [segment][kt][ct], contiguous.
static constexpr int OFF_W0    = 0;        // 4 kt x 8 ct
static constexpr int OFF_W1    = 16384;    // 16 x 8
static constexpr int OFF_W2    = 81920;
static constexpr int OFF_W3    = 147456;
static constexpr int OFF_W4    = 212992;
static constexpr int OFF_W5    = 278528;   // w5b (16x8) then w5a (4x8), contiguous = 20 slices
static constexpr int OFF_W6    = 360448;
static constexpr int OFF_W7    = 425984;
static constexpr int OFF_FEAT  = 491520;
static constexpr int OFF_VIEWS = 557056;   // viewsA (16x4) then viewsB (2x4) = 18 slices of 2048
static constexpr int OFF_RGB   = 593920;   // 8 x 1

struct Seg { const float* src; int k0, rv, fo, ct, t0; };
struct RepParams { Seg seg[13]; f16* rep; };

__global__ void repack_kernel(RepParams P) {
  int tile = blockIdx.x;
  int s = 0;
  #pragma unroll
  for (int i = 1; i < 13; ++i)
    if (tile >= P.seg[i].t0) s = i;
  const Seg sg = P.seg[s];
  int local = tile - sg.t0;
  int kt = local / sg.ct;
  int ct = local - kt * sg.ct;
  int l = threadIdx.x;
  int ch = ct * 32 + (l & 31);
  int kbase = kt * 16 + ((l >> 5) << 3);
  f16x8 v;
  #pragma unroll
  for (int j = 0; j < 8; ++j) {
    int k = kbase + j;
    float val = 0.f;
    if (k < sg.rv && ch < sg.fo) val = sg.src[(size_t)(sg.k0 + k) * sg.fo + ch];
    v[j] = (f16)val;
  }
  *(f16x8*)(P.rep + (size_t)tile * 512 + (size_t)l * 8) = v;
}

struct MainParams {
  const float* x;
  const float* b[8];
  const float* feat_b;
  const float* alpha_w;
  const float* alpha_b;
  const float* views_b;
  const float* rgb_b;
  const f16* rep;
  float* out;
};

// Activation LDS addressing: [pt<128][256ch] f16, 512 B rows, XOR swizzle.
__device__ __forceinline__ int act_off(int pt, int kbyte) {
  return pt * 512 + (kbyte ^ ((pt & 15) << 4));
}

// 256-out layer; block = 2 waves (ci = wave id), wave tile 128ch x 128pt
// (all 128 pts of the block). acc = 256 f32 -> AGPRs (unified file; 2 blocks/CU
// -> 2 waves/SIMD so TLP hides the global A-load latency). A-frags direct from
// global (L2-resident repack); B from act LDS.
template<int KTA, int KTX, bool RELU>
__device__ __forceinline__ void layer128d(
    const f16* repL, const float* bias,
    f16* act, const float* xrow0, int lane, int ci)
{
  const int l31 = lane & 31;
  const int ln5 = lane >> 5;
  const int chb = ci * 128;

  f32x16 acc[4][4];
  #pragma unroll
  for (int c = 0; c < 4; ++c) {
    #pragma unroll
    for (int g = 0; g < 4; ++g) {
      f32x4 bv = *(const f32x4*)(bias + chb + c * 32 + g * 8 + (ln5 << 2));
      #pragma unroll
      for (int p = 0; p < 4; ++p) {
        #pragma unroll
        for (int q = 0; q < 4; ++q) acc[c][p][g * 4 + q] = bv[q];
      }
    }
  }

  // Skip-connection part first (pos frags live only one j-step).
  #pragma unroll
  for (int j = 0; j < KTX; ++j) {
    f16x8 pf[4];
    #pragma unroll
    for (int p = 0; p < 4; ++p) {
      const float* row = xrow0 + (size_t)(p * 32 + l31) * 90;
      #pragma unroll
      for (int jj = 0; jj < 8; ++jj) {
        int c = j * 16 + ln5 * 8 + jj;
        pf[p][jj] = (f16)((c < 63) ? row[c] : 0.f);
      }
    }
    #pragma unroll
    for (int c = 0; c < 4; ++c) {
      f16x8 a = *(const f16x8*)(repL + (size_t)((KTA + j) * 8 + ci * 4 + c) * 512 + (size_t)lane * 8);
      #pragma unroll
      for (int p = 0; p < 4; ++p)
        acc[c][p] = __builtin_amdgcn_mfma_f32_32x32x16_f16(a, pf[p], acc[c][p], 0, 0, 0);
    }
  }

  __syncthreads();  // prev epilogue writes -> visible to our B reads

  #pragma unroll
  for (int kt = 0; kt < KTA; ++kt) {
    f16x8 a[4], bfr[4];
    #pragma unroll
    for (int c = 0; c < 4; ++c)
      a[c] = *(const f16x8*)(repL + (size_t)(kt * 8 + ci * 4 + c) * 512 + (size_t)lane * 8);
    #pragma unroll
    for (int p = 0; p < 4; ++p)
      bfr[p] = *(const f16x8*)((const char*)act + act_off(p * 32 + l31, (kt * 16 + ln5 * 8) * 2));
    #pragma unroll
    for (int c = 0; c < 4; ++c)
      #pragma unroll
      for (int p = 0; p < 4; ++p)
        acc[c][p] = __builtin_amdgcn_mfma_f32_32x32x16_f16(a[c], bfr[p], acc[c][p], 0, 0, 0);
  }

  __syncthreads();  // all B reads done -> safe to overwrite act in place

  // Epilogue: C row = (r&3) + 8*(r>>2) + 4*(l>>5), col = l&31 (pt).
  #pragma unroll
  for (int c = 0; c < 4; ++c) {
    #pragma unroll
    for (int p = 0; p < 4; ++p) {
      int pt = p * 32 + l31;
      #pragma unroll
      for (int g = 0; g < 4; ++g) {
        f16x4 h;
        #pragma unroll
        for (int q = 0; q < 4; ++q) {
          float v = acc[c][p][g * 4 + q];
          if (RELU) v = fmaxf(v, 0.f);
          h[q] = (f16)v;
        }
        int ch = chb + c * 32 + g * 8 + (ln5 << 2);
        *(f16x4*)((char*)act + act_off(pt, ch * 2)) = h;
      }
    }
  }
}

// Views layer: in = feature(256 from act) + views(27 gathered), out = 128 ch.
// Wave w -> ch [64w, 64w+64) (ct tiles 2w, 2w+1) x all 128 pts.
__device__ __forceinline__ void layer_views128(
    const f16* repL, const float* bias, f16* act,
    const float* xrow0, int lane, int w)
{
  const int l31 = lane & 31;
  const int ln5 = lane >> 5;
  const int chb = w * 64;

  f32x16 acc[2][4];
  #pragma unroll
  for (int c = 0; c < 2; ++c) {
    #pragma unroll
    for (int g = 0; g < 4; ++g) {
      f32x4 bv = *(const f32x4*)(bias + chb + c * 32 + g * 8 + (ln5 << 2));
      #pragma unroll
      for (int p = 0; p < 4; ++p)
        #pragma unroll
        for (int q = 0; q < 4; ++q) acc[c][p][g * 4 + q] = bv[q];
    }
  }

  // Views part first.
  #pragma unroll
  for (int j = 0; j < 2; ++j) {
    f16x8 vf[4];
    #pragma unroll
    for (int p = 0; p < 4; ++p) {
      const float* row = xrow0 + (size_t)(p * 32 + l31) * 90;
      #pragma unroll
      for (int jj = 0; jj < 8; ++jj) {
        int c = j * 16 + ln5 * 8 + jj;
        vf[p][jj] = (f16)((c < 27) ? row[63 + c] : 0.f);
      }
    }
    #pragma unroll
    for (int c = 0; c < 2; ++c) {
      f16x8 a = *(const f16x8*)(repL + (size_t)((16 + j) * 4 + 2 * w + c) * 512 + (size_t)lane * 8);
      #pragma unroll
      for (int p = 0; p < 4; ++p)
        acc[c][p] = __builtin_amdgcn_mfma_f32_32x32x16_f16(a, vf[p], acc[c][p], 0, 0, 0);
    }
  }

  __syncthreads();

  #pragma unroll
  for (int kt = 0; kt < 16; ++kt) {
    f16x8 a[2], bfr[4];
    #pragma unroll
    for (int c = 0; c < 2; ++c)
      a[c] = *(const f16x8*)(repL + (size_t)(kt * 4 + 2 * w + c) * 512 + (size_t)lane * 8);
    #pragma unroll
    for (int p = 0; p < 4; ++p)
      bfr[p] = *(const f16x8*)((const char*)act + act_off(p * 32 + l31, (kt * 16 + ln5 * 8) * 2));
    #pragma unroll
    for (int c = 0; c < 2; ++c)
      #pragma unroll
      for (int p = 0; p < 4; ++p)
        acc[c][p] = __builtin_amdgcn_mfma_f32_32x32x16_f16(a[c], bfr[p], acc[c][p], 0, 0, 0);
  }

  __syncthreads();

  #pragma unroll
  for (int c = 0; c < 2; ++c) {
    #pragma unroll
    for (int p = 0; p < 4; ++p) {
      int pt = p * 32 + l31;
      #pragma unroll
      for (int g = 0; g < 4; ++g) {
        f16x4 h;
        #pragma unroll
        for (int q = 0; q < 4; ++q) {
          float v = fmaxf(acc[c][p][g * 4 + q], 0.f);
          h[q] = (f16)v;
        }
        int ch = chb + c * 32 + g * 8 + (ln5 << 2);
        *(f16x4*)((char*)act + act_off(pt, ch * 2)) = h;
      }
    }
  }
}

// alpha = y . alpha_w + alpha_b, kept in a register (thread tid <-> pt tid).
__device__ __forceinline__ float alpha_pass(const f16* act, const float* aw,
                                            const float* ab, int tid)
{
  __syncthreads();
  float s = 0.f;
  #pragma unroll
  for (int i = 0; i < 32; ++i) {
    int k0 = i * 8;
    f16x8 v = *(const f16x8*)((const char*)act + act_off(tid, k0 * 2));
    f32x4 wa = *(const f32x4*)(aw + k0);
    f32x4 wb = *(const f32x4*)(aw + k0 + 4);
    #pragma unroll
    for (int q = 0; q < 4; ++q) {
      s += (float)v[q] * wa[q];
      s += (float)v[q + 4] * wb[q];
    }
  }
  return s + ab[0];
}

// rgb (128 -> 3 via padded 32-ch MFMA): wave w handles pts [64w, 64w+64).
// alpha from registers via intra-wave shuffle (lane l of wave w holds pt 64w+l).
__device__ __forceinline__ void layer_rgb_store(
    const f16* repL, f16* act, float alpha_val,
    const float* rgb_b, float* out, int pt0, int lane, int w)
{
  __syncthreads();
  f32x16 acc[2] = {};
  #pragma unroll
  for (int kt = 0; kt < 8; ++kt) {
    f16x8 a = *(const f16x8*)(repL + (size_t)kt * 512 + (size_t)lane * 8);
    #pragma unroll
    for (int p = 0; p < 2; ++p) {
      f16x8 b = *(const f16x8*)((const char*)act + act_off(w * 64 + p * 32 + (lane & 31), (kt * 16 + (lane >> 5) * 8) * 2));
      acc[p] = __builtin_amdgcn_mfma_f32_32x32x16_f16(a, b, acc[p], 0, 0, 0);
    }
  }
  float aw0 = __shfl(alpha_val, lane & 31);
  float aw1 = __shfl(alpha_val, 32 + (lane & 31));
  if (lane < 32) {
    #pragma unroll
    for (int p = 0; p < 2; ++p) {
      int pt = w * 64 + p * 32 + lane;
      float4 o;
      o.x = acc[p][0] + rgb_b[0];
      o.y = acc[p][1] + rgb_b[1];
      o.z = acc[p][2] + rgb_b[2];
      o.w = (p == 0) ? aw0 : aw1;
      *(float4*)(out + (size_t)(pt0 + pt) * 4) = o;
    }
  }
}

__global__ __launch_bounds__(128, 2) void nerf_main(MainParams P) {
  __shared__ __align__(16) f16 act[32768];   // 64 KB: [128 pt][256 k], swizzled

  const int tid = threadIdx.x;
  const int lane = tid & 63;
  const int w = tid >> 6;                // 2 waves: w == ci (ch-half)
  const int pt0 = blockIdx.x * 128;
  const float* xrow0 = P.x + (size_t)pt0 * 90;

  layer128d<0, 4, true>(P.rep + OFF_W0, P.b[0], act, xrow0, lane, w);
  layer128d<16, 0, true>(P.rep + OFF_W1, P.b[1], act, nullptr, lane, w);
  layer128d<16, 0, true>(P.rep + OFF_W2, P.b[2], act, nullptr, lane, w);
  layer128d<16, 0, true>(P.rep + OFF_W3, P.b[3], act, nullptr, lane, w);
  layer128d<16, 0, true>(P.rep + OFF_W4, P.b[4], act, nullptr, lane, w);
  layer128d<16, 4, true>(P.rep + OFF_W5, P.b[5], act, xrow0, lane, w);
  layer128d<16, 0, true>(P.rep + OFF_W6, P.b[6], act, nullptr, lane, w);
  layer128d<16, 0, true>(P.rep + OFF_W7, P.b[7], act, nullptr, lane, w);

  float alpha_val = alpha_pass(act, P.alpha_w, P.alpha_b, tid);

  layer128d<16, 0, false>(P.rep + OFF_FEAT, P.feat_b, act, nullptr, lane, w);

  layer_views128(P.rep + OFF_VIEWS, P.views_b, act, xrow0, lane, w);

  layer_rgb_store(P.rep + OFF_RGB, act, alpha_val, P.rgb_b, P.out, pt0, lane, w);

  // Second tuple output: zeros (N, 3) -> 384 floats per 128-pt block
  float* out2 = P.out + (size_t)NPTS * 4;
  if (tid < 96) {
    *(float4*)(out2 + (size_t)blockIdx.x * 384 + (size_t)tid * 4) =
        make_float4(0.f, 0.f, 0.f, 0.f);
  }
}

extern "C" void kernel_launch(void* const* d_in, const int* in_sizes, int n_in,
                              void* d_out, int out_size, void* d_ws, size_t ws_size,
                              hipStream_t stream) {
  (void)in_sizes; (void)n_in; (void)out_size; (void)ws_size;

  RepParams rp;
  rp.seg[0]  = { (const float*)d_in[1],    0,  63, 256, 8,    0 }; // w0 (pad K 63->64)
  rp.seg[1]  = { (const float*)d_in[3],    0, 256, 256, 8,   32 }; // w1
  rp.seg[2]  = { (const float*)d_in[5],    0, 256, 256, 8,  160 }; // w2
  rp.seg[3]  = { (const float*)d_in[7],    0, 256, 256, 8,  288 }; // w3
  rp.seg[4]  = { (const float*)d_in[9],    0, 256, 256, 8,  416 }; // w4
  rp.seg[5]  = { (const float*)d_in[11],  63, 256, 256, 8,  544 }; // w5 y-part (rows 63..318)
  rp.seg[6]  = { (const float*)d_in[11],   0,  63, 256, 8,  672 }; // w5 pos-part (rows 0..62)
  rp.seg[7]  = { (const float*)d_in[13],   0, 256, 256, 8,  704 }; // w6
  rp.seg[8]  = { (const float*)d_in[15],   0, 256, 256, 8,  832 }; // w7
  rp.seg[9]  = { (const float*)d_in[17],   0, 256, 256, 8,  960 }; // feat_w
  rp.seg[10] = { (const float*)d_in[21],   0, 256, 128, 4, 1088 }; // views_w feature-part
  rp.seg[11] = { (const float*)d_in[21], 256,  27, 128, 4, 1152 }; // views_w views-part
  rp.seg[12] = { (const float*)d_in[23],   0, 128,   3, 1, 1160 }; // rgb_w (pad 3->32 ch)
  rp.rep = (f16*)d_ws;
  repack_kernel<<<1168, 64, 0, stream>>>(rp);

  MainParams mp;
  mp.x = (const float*)d_in[0];
  for (int i = 0; i < 8; ++i) mp.b[i] = (const float*)d_in[2 + 2 * i];
  mp.feat_b  = (const float*)d_in[18];
  mp.alpha_w = (const float*)d_in[19];
  mp.alpha_b = (const float*)d_in[20];
  mp.views_b = (const float*)d_in[22];
  mp.rgb_b   = (const float*)d_in[24];
  mp.rep = (const f16*)d_ws;
  mp.out = (float*)d_out;
  nerf_main<<<2048, 128, 0, stream>>>(mp);
}

// Round 8
// 445.294 us; speedup vs baseline: 1.1076x; 1.0090x over previous
//
#include <hip/hip_runtime.h>
#include <cstdint>
#include <cstddef>

typedef _Float16 f16;
typedef _Float16 f16x8 __attribute__((ext_vector_type(8)));
typedef _Float16 f16x4 __attribute__((ext_vector_type(4)));
typedef float f32x16 __attribute__((ext_vector_type(16)));
typedef float f32x4 __attribute__((ext_vector_type(4)));

static constexpr int NPTS = 262144;

// Repacked weight offsets (in halfs). Each "tile" is 512 halfs = 64 lanes x 8.
// Fragment layout per tile (kt, ct): value = W[k][ch], k = kt*16 + (l>>5)*8 + j,
// ch = ct*32 + (l&31). Tiles ordered [segment][kt][ct], contiguous.
static constexpr int OFF_W0    = 0;        // 4 kt x 8 ct
static constexpr int OFF_W1    = 16384;    // 16 x 8
static constexpr int OFF_W2    = 81920;
static constexpr int OFF_W3    = 147456;
static constexpr int OFF_W4    = 212992;
static constexpr int OFF_W5    = 278528;   // w5b (16x8) then w5a (4x8), contiguous = 20 slices
static constexpr int OFF_W6    = 360448;
static constexpr int OFF_W7    = 425984;
static constexpr int OFF_FEAT  = 491520;
static constexpr int OFF_VIEWS = 557056;   // viewsA (16x4) then viewsB (2x4) = 18 slices of 2048
static constexpr int OFF_RGB   = 593920;   // 8 x 1

struct Seg { const float* src; int k0, rv, fo, ct, t0; };
struct RepParams { Seg seg[13]; f16* rep; };

__global__ void repack_kernel(RepParams P) {
  int tile = blockIdx.x;
  int s = 0;
  #pragma unroll
  for (int i = 1; i < 13; ++i)
    if (tile >= P.seg[i].t0) s = i;
  const Seg sg = P.seg[s];
  int local = tile - sg.t0;
  int kt = local / sg.ct;
  int ct = local - kt * sg.ct;
  int l = threadIdx.x;
  int ch = ct * 32 + (l & 31);
  int kbase = kt * 16 + ((l >> 5) << 3);
  f16x8 v;
  #pragma unroll
  for (int j = 0; j < 8; ++j) {
    int k = kbase + j;
    float val = 0.f;
    if (k < sg.rv && ch < sg.fo) val = sg.src[(size_t)(sg.k0 + k) * sg.fo + ch];
    v[j] = (f16)val;
  }
  *(f16x8*)(P.rep + (size_t)tile * 512 + (size_t)l * 8) = v;
}

struct MainParams {
  const float* x;
  const float* b[8];
  const float* feat_b;
  const float* alpha_w;
  const float* alpha_b;
  const float* views_b;
  const float* rgb_b;
  const f16* rep;
  float* out;
};

// Activation LDS: [pt<64][256ch] f16, 512 B rows, XOR swizzle (conflict-free
// B-frag ds_read_b128).
__device__ __forceinline__ int act_off(int pt, int kbyte) {
  return pt * 512 + (kbyte ^ ((pt & 15) << 4));
}
// pos cache LDS: [pt<64][64ch] f16, 128 B rows, XOR swizzle (4-way worst case,
// only read in 2 layers).
__device__ __forceinline__ int pos_off(int pt, int kbyte) {
  return pt * 128 + (kbyte ^ ((pt & 7) << 4));
}

// Standard 256-out layer, 64-pt block, 4 waves. Wave w computes ch [64w,64w+64)
// x all 64 pts: acc[c][p] (ct = 2w+c, p = pt-half), D[ch][pt].
// A-frags straight from global (L2-resident repack). B-frags: KTA kt-tiles from
// act, then (if POSB) 4 kt-tiles from the posb cache (A slices KTA..KTA+3).
template<int KTA, bool POSB, bool RELU>
__device__ __forceinline__ void layer_std64(
    const f16* repL, const float* bias,
    f16* act, const f16* posb, int lane, int w)
{
  const int l31 = lane & 31;
  const int ln5 = lane >> 5;
  const int chb = w * 64;

  f32x16 acc[2][2];
  #pragma unroll
  for (int c = 0; c < 2; ++c) {
    #pragma unroll
    for (int g = 0; g < 4; ++g) {
      f32x4 bv = *(const f32x4*)(bias + chb + c * 32 + g * 8 + (ln5 << 2));
      #pragma unroll
      for (int q = 0; q < 4; ++q) {
        acc[c][0][g * 4 + q] = bv[q];
        acc[c][1][g * 4 + q] = bv[q];
      }
    }
  }

  __syncthreads();  // prev epilogue writes (and prologue posb fill) visible

  if (POSB) {
    #pragma unroll
    for (int j = 0; j < 4; ++j) {
      f16x8 a[2], bfr[2];
      #pragma unroll
      for (int c = 0; c < 2; ++c)
        a[c] = *(const f16x8*)(repL + (size_t)((KTA + j) * 8 + 2 * w + c) * 512 + (size_t)lane * 8);
      #pragma unroll
      for (int p = 0; p < 2; ++p)
        bfr[p] = *(const f16x8*)((const char*)posb + pos_off(p * 32 + l31, (j * 16 + ln5 * 8) * 2));
      #pragma unroll
      for (int c = 0; c < 2; ++c)
        #pragma unroll
        for (int p = 0; p < 2; ++p)
          acc[c][p] = __builtin_amdgcn_mfma_f32_32x32x16_f16(a[c], bfr[p], acc[c][p], 0, 0, 0);
    }
  }

  #pragma unroll
  for (int kt = 0; kt < KTA; ++kt) {
    f16x8 a[2], bfr[2];
    #pragma unroll
    for (int c = 0; c < 2; ++c)
      a[c] = *(const f16x8*)(repL + (size_t)(kt * 8 + 2 * w + c) * 512 + (size_t)lane * 8);
    #pragma unroll
    for (int p = 0; p < 2; ++p)
      bfr[p] = *(const f16x8*)((const char*)act + act_off(p * 32 + l31, (kt * 16 + ln5 * 8) * 2));
    #pragma unroll
    for (int c = 0; c < 2; ++c)
      #pragma unroll
      for (int p = 0; p < 2; ++p)
        acc[c][p] = __builtin_amdgcn_mfma_f32_32x32x16_f16(a[c], bfr[p], acc[c][p], 0, 0, 0);
  }

  __syncthreads();  // all B reads done -> safe to overwrite act in place

  // Epilogue: C row = (r&3) + 8*(r>>2) + 4*(l>>5), col = l&31 (pt).
  #pragma unroll
  for (int c = 0; c < 2; ++c) {
    #pragma unroll
    for (int p = 0; p < 2; ++p) {
      int pt = p * 32 + l31;
      #pragma unroll
      for (int g = 0; g < 4; ++g) {
        f16x4 h;
        #pragma unroll
        for (int q = 0; q < 4; ++q) {
          float v = acc[c][p][g * 4 + q];
          if (RELU) v = fmaxf(v, 0.f);
          h[q] = (f16)v;
        }
        int ch = chb + c * 32 + g * 8 + (ln5 << 2);
        *(f16x4*)((char*)act + act_off(pt, ch * 2)) = h;
      }
    }
  }
}

// Views layer: in = feature(256 from act) + views(27 gathered from x), out=128.
// Wave w -> ch [32w, 32w+32) x 64 pts.
__device__ __forceinline__ void layer_views64(
    const f16* repL, const float* bias, f16* act,
    const float* xrow0, int lane, int w)
{
  const int l31 = lane & 31;
  const int ln5 = lane >> 5;
  const int chb = w * 32;

  f32x16 acc[2];
  #pragma unroll
  for (int g = 0; g < 4; ++g) {
    f32x4 bv = *(const f32x4*)(bias + chb + g * 8 + (ln5 << 2));
    #pragma unroll
    for (int q = 0; q < 4; ++q) {
      acc[0][g * 4 + q] = bv[q];
      acc[1][g * 4 + q] = bv[q];
    }
  }

  // Views part first (vb gathered, lives briefly).
  #pragma unroll
  for (int j = 0; j < 2; ++j) {
    f16x8 vf[2];
    #pragma unroll
    for (int p = 0; p < 2; ++p) {
      const float* row = xrow0 + (size_t)(p * 32 + l31) * 90;
      #pragma unroll
      for (int jj = 0; jj < 8; ++jj) {
        int c = j * 16 + ln5 * 8 + jj;
        vf[p][jj] = (f16)((c < 27) ? row[63 + c] : 0.f);
      }
    }
    f16x8 a = *(const f16x8*)(repL + (size_t)((16 + j) * 4 + w) * 512 + (size_t)lane * 8);
    #pragma unroll
    for (int p = 0; p < 2; ++p)
      acc[p] = __builtin_amdgcn_mfma_f32_32x32x16_f16(a, vf[p], acc[p], 0, 0, 0);
  }

  __syncthreads();

  #pragma unroll
  for (int kt = 0; kt < 16; ++kt) {
    f16x8 a = *(const f16x8*)(repL + (size_t)(kt * 4 + w) * 512 + (size_t)lane * 8);
    f16x8 bfr[2];
    #pragma unroll
    for (int p = 0; p < 2; ++p)
      bfr[p] = *(const f16x8*)((const char*)act + act_off(p * 32 + l31, (kt * 16 + ln5 * 8) * 2));
    #pragma unroll
    for (int p = 0; p < 2; ++p)
      acc[p] = __builtin_amdgcn_mfma_f32_32x32x16_f16(a, bfr[p], acc[p], 0, 0, 0);
  }

  __syncthreads();

  #pragma unroll
  for (int p = 0; p < 2; ++p) {
    int pt = p * 32 + l31;
    #pragma unroll
    for (int g = 0; g < 4; ++g) {
      f16x4 h;
      #pragma unroll
      for (int q = 0; q < 4; ++q) {
        float v = fmaxf(acc[p][g * 4 + q], 0.f);
        h[q] = (f16)v;
      }
      int ch = chb + g * 8 + (ln5 << 2);
      *(f16x4*)((char*)act + act_off(pt, ch * 2)) = h;
    }
  }
}

// alpha = y . alpha_w + alpha_b. Thread t: pt = t>>2, quarter q = t&3 sums
// k in [64q, 64q+64); intra-wave shfl_xor reduce (lanes pt*4+q are same-wave).
__device__ __forceinline__ void alpha_pass(const f16* act, const float* aw,
                                           const float* ab, float* alds, int tid)
{
  __syncthreads();
  int pt = tid >> 2;
  int q = tid & 3;
  float s = 0.f;
  #pragma unroll
  for (int i = 0; i < 8; ++i) {
    int k0 = q * 64 + i * 8;
    f16x8 v = *(const f16x8*)((const char*)act + act_off(pt, k0 * 2));
    f32x4 wa = *(const f32x4*)(aw + k0);
    f32x4 wb = *(const f32x4*)(aw + k0 + 4);
    #pragma unroll
    for (int j = 0; j < 4; ++j) {
      s += (float)v[j] * wa[j];
      s += (float)v[j + 4] * wb[j];
    }
  }
  s += __shfl_xor(s, 1);
  s += __shfl_xor(s, 2);
  if (q == 0) alds[pt] = s + ab[0];
}

// rgb (128 -> 3 via one padded 32-ch MFMA tile) + packed store. Waves 0,1.
__device__ __forceinline__ void layer_rgb_store(
    const f16* repL, f16* act, const float* alds,
    const float* rgb_b, float* out, int pt0, int lane, int w)
{
  __syncthreads();
  if (w < 2) {
    f32x16 acc = {};
    #pragma unroll
    for (int kt = 0; kt < 8; ++kt) {
      f16x8 a = *(const f16x8*)(repL + (size_t)kt * 512 + (size_t)lane * 8);
      f16x8 b = *(const f16x8*)((const char*)act + act_off(w * 32 + (lane & 31), (kt * 16 + (lane >> 5) * 8) * 2));
      acc = __builtin_amdgcn_mfma_f32_32x32x16_f16(a, b, acc, 0, 0, 0);
    }
    if (lane < 32) {
      int pt = w * 32 + lane;
      float4 o;
      o.x = acc[0] + rgb_b[0];
      o.y = acc[1] + rgb_b[1];
      o.z = acc[2] + rgb_b[2];
      o.w = alds[pt];
      *(float4*)(out + (size_t)(pt0 + pt) * 4) = o;
    }
  }
}

__global__ __launch_bounds__(256, 4) void nerf_main(MainParams P) {
  __shared__ __align__(16) f16 act[16384];   // 32 KB: [64 pt][256 k], swizzled
  __shared__ __align__(16) f16 posb[4096];   // 8 KB: [64 pt][64 k] pos cache

  const int tid = threadIdx.x;
  const int lane = tid & 63;
  const int w = tid >> 6;
  const int pt0 = blockIdx.x * 64;
  const float* xrow0 = P.x + (size_t)pt0 * 90;

  // Prologue: gather pos (63 ch, pad to 64) into posb ONCE, f16, B-frag layout.
  {
    int pt = tid & 63;
    int q = tid >> 6;
    const float* row = xrow0 + (size_t)pt * 90;
    #pragma unroll
    for (int h = 0; h < 2; ++h) {
      f16x8 v;
      #pragma unroll
      for (int jj = 0; jj < 8; ++jj) {
        int k = q * 16 + h * 8 + jj;
        v[jj] = (f16)((k < 63) ? row[k] : 0.f);
      }
      *(f16x8*)((char*)posb + pos_off(pt, (q * 16 + h * 8) * 2)) = v;
    }
  }

  layer_std64<0, true, true>(P.rep + OFF_W0, P.b[0], act, posb, lane, w);
  layer_std64<16, false, true>(P.rep + OFF_W1, P.b[1], act, posb, lane, w);
  layer_std64<16, false, true>(P.rep + OFF_W2, P.b[2], act, posb, lane, w);
  layer_std64<16, false, true>(P.rep + OFF_W3, P.b[3], act, posb, lane, w);
  layer_std64<16, false, true>(P.rep + OFF_W4, P.b[4], act, posb, lane, w);
  layer_std64<16, true, true>(P.rep + OFF_W5, P.b[5], act, posb, lane, w);
  layer_std64<16, false, true>(P.rep + OFF_W6, P.b[6], act, posb, lane, w);
  layer_std64<16, false, true>(P.rep + OFF_W7, P.b[7], act, posb, lane, w);

  // posb is dead after L5 -> reuse as alpha scratch.
  float* alds = (float*)posb;
  alpha_pass(act, P.alpha_w, P.alpha_b, alds, tid);

  layer_std64<16, false, false>(P.rep + OFF_FEAT, P.feat_b, act, posb, lane, w);

  layer_views64(P.rep + OFF_VIEWS, P.views_b, act, xrow0, lane, w);

  layer_rgb_store(P.rep + OFF_RGB, act, alds, P.rgb_b, P.out, pt0, lane, w);

  // Second tuple output: zeros (N, 3) -> 192 floats per 64-pt block
  float* out2 = P.out + (size_t)NPTS * 4;
  if (tid < 48) {
    *(float4*)(out2 + (size_t)blockIdx.x * 192 + (size_t)tid * 4) =
        make_float4(0.f, 0.f, 0.f, 0.f);
  }
}

extern "C" void kernel_launch(void* const* d_in, const int* in_sizes, int n_in,
                              void* d_out, int out_size, void* d_ws, size_t ws_size,
                              hipStream_t stream) {
  (void)in_sizes; (void)n_in; (void)out_size; (void)ws_size;

  RepParams rp;
  rp.seg[0]  = { (const float*)d_in[1],    0,  63, 256, 8,    0 }; // w0 (pad K 63->64)
  rp.seg[1]  = { (const float*)d_in[3],    0, 256, 256, 8,   32 }; // w1
  rp.seg[2]  = { (const float*)d_in[5],    0, 256, 256, 8,  160 }; // w2
  rp.seg[3]  = { (const float*)d_in[7],    0, 256, 256, 8,  288 }; // w3
  rp.seg[4]  = { (const float*)d_in[9],    0, 256, 256, 8,  416 }; // w4
  rp.seg[5]  = { (const float*)d_in[11],  63, 256, 256, 8,  544 }; // w5 y-part (rows 63..318)
  rp.seg[6]  = { (const float*)d_in[11],   0,  63, 256, 8,  672 }; // w5 pos-part (rows 0..62)
  rp.seg[7]  = { (const float*)d_in[13],   0, 256, 256, 8,  704 }; // w6
  rp.seg[8]  = { (const float*)d_in[15],   0, 256, 256, 8,  832 }; // w7
  rp.seg[9]  = { (const float*)d_in[17],   0, 256, 256, 8,  960 }; // feat_w
  rp.seg[10] = { (const float*)d_in[21],   0, 256, 128, 4, 1088 }; // views_w feature-part
  rp.seg[11] = { (const float*)d_in[21], 256,  27, 128, 4, 1152 }; // views_w views-part
  rp.seg[12] = { (const float*)d_in[23],   0, 128,   3, 1, 1160 }; // rgb_w (pad 3->32 ch)
  rp.rep = (f16*)d_ws;
  repack_kernel<<<1168, 64, 0, stream>>>(rp);

  MainParams mp;
  mp.x = (const float*)d_in[0];
  for (int i = 0; i < 8; ++i) mp.b[i] = (const float*)d_in[2 + 2 * i];
  mp.feat_b  = (const float*)d_in[18];
  mp.alpha_w = (const float*)d_in[19];
  mp.alpha_b = (const float*)d_in[20];
  mp.views_b = (const float*)d_in[22];
  mp.rgb_b   = (const float*)d_in[24];
  mp.rep = (const f16*)d_ws;
  mp.out = (float*)d_out;
  nerf_main<<<4096, 256, 0, stream>>>(mp);
}

// Round 9
// 347.954 us; speedup vs baseline: 1.4175x; 1.2797x over previous
//
#include <hip/hip_runtime.h>
#include <cstdint>
#include <cstddef>

typedef _Float16 f16;
typedef _Float16 f16x8 __attribute__((ext_vector_type(8)));
typedef _Float16 f16x4 __attribute__((ext_vector_type(4)));
typedef float f32x16 __attribute__((ext_vector_type(16)));
typedef float f32x4 __attribute__((ext_vector_type(4)));

static constexpr int NPTS = 262144;

// Repacked weight offsets (in halfs). Each "tile" is 512 halfs = 64 lanes x 8.
// Fragment layout per tile (kt, ct): value = W[k][ch], k = kt*16 + (l>>5)*8 + j,
// ch = ct*32 + (l&31). Tiles ordered [segment][kt][ct], contiguous.
static constexpr int OFF_W0    = 0;        // 4 kt x 8 ct
static constexpr int OFF_W1    = 16384;    // 16 x 8
static constexpr int OFF_W2    = 81920;
static constexpr int OFF_W3    = 147456;
static constexpr int OFF_W4    = 212992;
static constexpr int OFF_W5    = 278528;   // w5b (16x8) then w5a (4x8), contiguous = 20 slices
static constexpr int OFF_W6    = 360448;
static constexpr int OFF_W7    = 425984;
static constexpr int OFF_FEAT  = 491520;
static constexpr int OFF_VIEWS = 557056;   // viewsA (16x4) then viewsB (2x4) = 18 slices of 2048
static constexpr int OFF_RGB   = 593920;   // 8 x 1

struct Seg { const float* src; int k0, rv, fo, ct, t0; };
struct RepParams { Seg seg[13]; f16* rep; };

__global__ void repack_kernel(RepParams P) {
  int tile = blockIdx.x;
  int s = 0;
  #pragma unroll
  for (int i = 1; i < 13; ++i)
    if (tile >= P.seg[i].t0) s = i;
  const Seg sg = P.seg[s];
  int local = tile - sg.t0;
  int kt = local / sg.ct;
  int ct = local - kt * sg.ct;
  int l = threadIdx.x;
  int ch = ct * 32 + (l & 31);
  int kbase = kt * 16 + ((l >> 5) << 3);
  f16x8 v;
  #pragma unroll
  for (int j = 0; j < 8; ++j) {
    int k = kbase + j;
    float val = 0.f;
    if (k < sg.rv && ch < sg.fo) val = sg.src[(size_t)(sg.k0 + k) * sg.fo + ch];
    v[j] = (f16)val;
  }
  *(f16x8*)(P.rep + (size_t)tile * 512 + (size_t)l * 8) = v;
}

struct MainParams {
  const float* x;
  const float* b[8];
  const float* feat_b;
  const float* alpha_w;
  const float* alpha_b;
  const float* views_b;
  const float* rgb_b;
  const f16* rep;
  float* out;
};

// Activation LDS: [pt<128][256ch] f16, 512 B rows, XOR swizzle (conflict-free
// B-frag ds_read_b128).
__device__ __forceinline__ int act_off(int pt, int kbyte) {
  return pt * 512 + (kbyte ^ ((pt & 15) << 4));
}
// pos cache LDS: [pt<128][64ch] f16, 128 B rows, XOR swizzle (4-way worst
// case, read in 2 layers only).
__device__ __forceinline__ int pos_off(int pt, int kbyte) {
  return pt * 128 + (kbyte ^ ((pt & 7) << 4));
}

// 256-out layer; block = 4 waves, wave w computes ch [64w, 64w+64) x ALL
// 128 pts: acc[c][p] (ct = 2w+c, p<4 pt tiles) = 128 f32. 2 blocks/CU ->
// 2 waves/SIMD. A-frags direct from global (L1/L2-resident repack; 32 B/cyc/CU
// instantaneous demand at full MFMA pipe = half of L1 capacity). B from LDS.
template<int KTA, bool POSB, bool RELU>
__device__ __forceinline__ void layer_std128(
    const f16* repL, const float* bias,
    f16* act, const f16* posb, int lane, int w)
{
  const int l31 = lane & 31;
  const int ln5 = lane >> 5;
  const int chb = w * 64;

  f32x16 acc[2][4];
  #pragma unroll
  for (int c = 0; c < 2; ++c) {
    #pragma unroll
    for (int g = 0; g < 4; ++g) {
      f32x4 bv = *(const f32x4*)(bias + chb + c * 32 + g * 8 + (ln5 << 2));
      #pragma unroll
      for (int p = 0; p < 4; ++p) {
        #pragma unroll
        for (int q = 0; q < 4; ++q) acc[c][p][g * 4 + q] = bv[q];
      }
    }
  }

  __syncthreads();  // prev epilogue writes (and prologue posb fill) visible

  if (POSB) {
    #pragma unroll
    for (int j = 0; j < 4; ++j) {
      f16x8 a[2], bfr[4];
      #pragma unroll
      for (int c = 0; c < 2; ++c)
        a[c] = *(const f16x8*)(repL + (size_t)((KTA + j) * 8 + 2 * w + c) * 512 + (size_t)lane * 8);
      #pragma unroll
      for (int p = 0; p < 4; ++p)
        bfr[p] = *(const f16x8*)((const char*)posb + pos_off(p * 32 + l31, (j * 16 + ln5 * 8) * 2));
      #pragma unroll
      for (int c = 0; c < 2; ++c)
        #pragma unroll
        for (int p = 0; p < 4; ++p)
          acc[c][p] = __builtin_amdgcn_mfma_f32_32x32x16_f16(a[c], bfr[p], acc[c][p], 0, 0, 0);
    }
  }

  #pragma unroll
  for (int kt = 0; kt < KTA; ++kt) {
    f16x8 a[2], bfr[4];
    #pragma unroll
    for (int c = 0; c < 2; ++c)
      a[c] = *(const f16x8*)(repL + (size_t)(kt * 8 + 2 * w + c) * 512 + (size_t)lane * 8);
    #pragma unroll
    for (int p = 0; p < 4; ++p)
      bfr[p] = *(const f16x8*)((const char*)act + act_off(p * 32 + l31, (kt * 16 + ln5 * 8) * 2));
    #pragma unroll
    for (int c = 0; c < 2; ++c)
      #pragma unroll
      for (int p = 0; p < 4; ++p)
        acc[c][p] = __builtin_amdgcn_mfma_f32_32x32x16_f16(a[c], bfr[p], acc[c][p], 0, 0, 0);
  }

  __syncthreads();  // all B reads done -> safe to overwrite act in place

  // Epilogue: C row = (r&3) + 8*(r>>2) + 4*(l>>5), col = l&31 (pt).
  #pragma unroll
  for (int c = 0; c < 2; ++c) {
    #pragma unroll
    for (int p = 0; p < 4; ++p) {
      int pt = p * 32 + l31;
      #pragma unroll
      for (int g = 0; g < 4; ++g) {
        f16x4 h;
        #pragma unroll
        for (int q = 0; q < 4; ++q) {
          float v = acc[c][p][g * 4 + q];
          if (RELU) v = fmaxf(v, 0.f);
          h[q] = (f16)v;
        }
        int ch = chb + c * 32 + g * 8 + (ln5 << 2);
        *(f16x4*)((char*)act + act_off(pt, ch * 2)) = h;
      }
    }
  }
}

// Views layer: in = feature(256 from act) + views(27 gathered from x), out=128.
// Wave w -> ch [32w, 32w+32) x all 128 pts.
__device__ __forceinline__ void layer_views128(
    const f16* repL, const float* bias, f16* act,
    const float* xrow0, int lane, int w)
{
  const int l31 = lane & 31;
  const int ln5 = lane >> 5;
  const int chb = w * 32;

  f32x16 acc[4];
  #pragma unroll
  for (int g = 0; g < 4; ++g) {
    f32x4 bv = *(const f32x4*)(bias + chb + g * 8 + (ln5 << 2));
    #pragma unroll
    for (int p = 0; p < 4; ++p)
      #pragma unroll
      for (int q = 0; q < 4; ++q) acc[p][g * 4 + q] = bv[q];
  }

  // Views part first (vf gathered, lives briefly).
  #pragma unroll
  for (int j = 0; j < 2; ++j) {
    f16x8 vf[4];
    #pragma unroll
    for (int p = 0; p < 4; ++p) {
      const float* row = xrow0 + (size_t)(p * 32 + l31) * 90;
      #pragma unroll
      for (int jj = 0; jj < 8; ++jj) {
        int c = j * 16 + ln5 * 8 + jj;
        vf[p][jj] = (f16)((c < 27) ? row[63 + c] : 0.f);
      }
    }
    f16x8 a = *(const f16x8*)(repL + (size_t)((16 + j) * 4 + w) * 512 + (size_t)lane * 8);
    #pragma unroll
    for (int p = 0; p < 4; ++p)
      acc[p] = __builtin_amdgcn_mfma_f32_32x32x16_f16(a, vf[p], acc[p], 0, 0, 0);
  }

  __syncthreads();

  #pragma unroll
  for (int kt = 0; kt < 16; ++kt) {
    f16x8 a = *(const f16x8*)(repL + (size_t)(kt * 4 + w) * 512 + (size_t)lane * 8);
    f16x8 bfr[4];
    #pragma unroll
    for (int p = 0; p < 4; ++p)
      bfr[p] = *(const f16x8*)((const char*)act + act_off(p * 32 + l31, (kt * 16 + ln5 * 8) * 2));
    #pragma unroll
    for (int p = 0; p < 4; ++p)
      acc[p] = __builtin_amdgcn_mfma_f32_32x32x16_f16(a, bfr[p], acc[p], 0, 0, 0);
  }

  __syncthreads();

  #pragma unroll
  for (int p = 0; p < 4; ++p) {
    int pt = p * 32 + l31;
    #pragma unroll
    for (int g = 0; g < 4; ++g) {
      f16x4 h;
      #pragma unroll
      for (int q = 0; q < 4; ++q) {
        float v = fmaxf(acc[p][g * 4 + q], 0.f);
        h[q] = (f16)v;
      }
      int ch = chb + g * 8 + (ln5 << 2);
      *(f16x4*)((char*)act + act_off(pt, ch * 2)) = h;
    }
  }
}

// alpha = y . alpha_w + alpha_b. 2 threads per point (128 pts, 256 threads),
// intra-wave shfl reduce; result into alds (reused posb memory).
__device__ __forceinline__ void alpha_pass(const f16* act, const float* aw,
                                           const float* ab, float* alds, int tid)
{
  __syncthreads();
  int pt = tid >> 1;
  int h = tid & 1;
  float s = 0.f;
  #pragma unroll
  for (int i = 0; i < 16; ++i) {
    int k0 = h * 128 + i * 8;
    f16x8 v = *(const f16x8*)((const char*)act + act_off(pt, k0 * 2));
    f32x4 wa = *(const f32x4*)(aw + k0);
    f32x4 wb = *(const f32x4*)(aw + k0 + 4);
    #pragma unroll
    for (int q = 0; q < 4; ++q) {
      s += (float)v[q] * wa[q];
      s += (float)v[q + 4] * wb[q];
    }
  }
  s += __shfl_xor(s, 1);
  if (h == 0) alds[pt] = s + ab[0];
}

// rgb (128 -> 3 via one padded 32-ch MFMA tile per wave) + packed store.
__device__ __forceinline__ void layer_rgb_store(
    const f16* repL, f16* act, const float* alds,
    const float* rgb_b, float* out, int pt0, int lane, int w)
{
  __syncthreads();
  f32x16 acc = {};
  #pragma unroll
  for (int kt = 0; kt < 8; ++kt) {
    f16x8 a = *(const f16x8*)(repL + (size_t)kt * 512 + (size_t)lane * 8);
    f16x8 b = *(const f16x8*)((const char*)act + act_off(w * 32 + (lane & 31), (kt * 16 + (lane >> 5) * 8) * 2));
    acc = __builtin_amdgcn_mfma_f32_32x32x16_f16(a, b, acc, 0, 0, 0);
  }
  if (lane < 32) {
    int pt = w * 32 + lane;
    float4 o;
    o.x = acc[0] + rgb_b[0];
    o.y = acc[1] + rgb_b[1];
    o.z = acc[2] + rgb_b[2];
    o.w = alds[pt];
    *(float4*)(out + (size_t)(pt0 + pt) * 4) = o;
  }
}

__global__ __launch_bounds__(256, 2) void nerf_main(MainParams P) {
  __shared__ __align__(16) f16 act[32768];   // 64 KB: [128 pt][256 k], swizzled
  __shared__ __align__(16) f16 posb[8192];   // 16 KB: [128 pt][64 k] pos cache

  const int tid = threadIdx.x;
  const int lane = tid & 63;
  const int w = tid >> 6;
  const int pt0 = blockIdx.x * 128;
  const float* xrow0 = P.x + (size_t)pt0 * 90;

  // Prologue: gather pos (63 ch, pad to 64) into posb ONCE, B-frag layout.
  // 256 threads: thread -> pt = tid&127, col-half q = tid>>7 (32 ch each).
  {
    int pt = tid & 127;
    int q = tid >> 7;
    const float* row = xrow0 + (size_t)pt * 90;
    #pragma unroll
    for (int h = 0; h < 4; ++h) {
      f16x8 v;
      #pragma unroll
      for (int jj = 0; jj < 8; ++jj) {
        int k = q * 32 + h * 8 + jj;
        v[jj] = (f16)((k < 63) ? row[k] : 0.f);
      }
      *(f16x8*)((char*)posb + pos_off(pt, (q * 32 + h * 8) * 2)) = v;
    }
  }

  layer_std128<0, true, true>(P.rep + OFF_W0, P.b[0], act, posb, lane, w);
  layer_std128<16, false, true>(P.rep + OFF_W1, P.b[1], act, posb, lane, w);
  layer_std128<16, false, true>(P.rep + OFF_W2, P.b[2], act, posb, lane, w);
  layer_std128<16, false, true>(P.rep + OFF_W3, P.b[3], act, posb, lane, w);
  layer_std128<16, false, true>(P.rep + OFF_W4, P.b[4], act, posb, lane, w);
  layer_std128<16, true, true>(P.rep + OFF_W5, P.b[5], act, posb, lane, w);
  layer_std128<16, false, true>(P.rep + OFF_W6, P.b[6], act, posb, lane, w);
  layer_std128<16, false, true>(P.rep + OFF_W7, P.b[7], act, posb, lane, w);

  // posb is dead after L5 -> reuse as alpha scratch.
  float* alds = (float*)posb;
  alpha_pass(act, P.alpha_w, P.alpha_b, alds, tid);

  layer_std128<16, false, false>(P.rep + OFF_FEAT, P.feat_b, act, posb, lane, w);

  layer_views128(P.rep + OFF_VIEWS, P.views_b, act, xrow0, lane, w);

  layer_rgb_store(P.rep + OFF_RGB, act, alds, P.rgb_b, P.out, pt0, lane, w);

  // Second tuple output: zeros (N, 3) -> 384 floats per 128-pt block
  float* out2 = P.out + (size_t)NPTS * 4;
  if (tid < 96) {
    *(float4*)(out2 + (size_t)blockIdx.x * 384 + (size_t)tid * 4) =
        make_float4(0.f, 0.f, 0.f, 0.f);
  }
}

extern "C" void kernel_launch(void* const* d_in, const int* in_sizes, int n_in,
                              void* d_out, int out_size, void* d_ws, size_t ws_size,
                              hipStream_t stream) {
  (void)in_sizes; (void)n_in; (void)out_size; (void)ws_size;

  RepParams rp;
  rp.seg[0]  = { (const float*)d_in[1],    0,  63, 256, 8,    0 }; // w0 (pad K 63->64)
  rp.seg[1]  = { (const float*)d_in[3],    0, 256, 256, 8,   32 }; // w1
  rp.seg[2]  = { (const float*)d_in[5],    0, 256, 256, 8,  160 }; // w2
  rp.seg[3]  = { (const float*)d_in[7],    0, 256, 256, 8,  288 }; // w3
  rp.seg[4]  = { (const float*)d_in[9],    0, 256, 256, 8,  416 }; // w4
  rp.seg[5]  = { (const float*)d_in[11],  63, 256, 256, 8,  544 }; // w5 y-part (rows 63..318)
  rp.seg[6]  = { (const float*)d_in[11],   0,  63, 256, 8,  672 }; // w5 pos-part (rows 0..62)
  rp.seg[7]  = { (const float*)d_in[13],   0, 256, 256, 8,  704 }; // w6
  rp.seg[8]  = { (const float*)d_in[15],   0, 256, 256, 8,  832 }; // w7
  rp.seg[9]  = { (const float*)d_in[17],   0, 256, 256, 8,  960 }; // feat_w
  rp.seg[10] = { (const float*)d_in[21],   0, 256, 128, 4, 1088 }; // views_w feature-part
  rp.seg[11] = { (const float*)d_in[21], 256,  27, 128, 4, 1152 }; // views_w views-part
  rp.seg[12] = { (const float*)d_in[23],   0, 128,   3, 1, 1160 }; // rgb_w (pad 3->32 ch)
  rp.rep = (f16*)d_ws;
  repack_kernel<<<1168, 64, 0, stream>>>(rp);

  MainParams mp;
  mp.x = (const float*)d_in[0];
  for (int i = 0; i < 8; ++i) mp.b[i] = (const float*)d_in[2 + 2 * i];
  mp.feat_b  = (const float*)d_in[18];
  mp.alpha_w = (const float*)d_in[19];
  mp.alpha_b = (const float*)d_in[20];
  mp.views_b = (const float*)d_in[22];
  mp.rgb_b   = (const float*)d_in[24];
  mp.rep = (const f16*)d_ws;
  mp.out = (float*)d_out;
  nerf_main<<<2048, 256, 0, stream>>>(mp);
}